// Round 3
// baseline (2180.933 us; speedup 1.0000x reference)
//
#include <hip/hip_runtime.h>
#include <hip/hip_bf16.h>

#define DD   256
#define NH   8
#define HDIM 32
#define LV   4
#define NP   4
#define DFF  2048
#define BB   4
#define NQQ  900
#define SS   21760

__device__ inline void stval(float* p, float v) { *p = v; }
__device__ inline void stval(__hip_bfloat16* p, float v) { *p = __float2bfloat16(v); }

// ---------------- generic tiled GEMM: C = A[MxK] @ W[KxN] + bias, opt relu ----
#define TS 16
template <typename OT>
__global__ void gemm_bias(const float* __restrict__ A, const float* __restrict__ W,
                          const float* __restrict__ bias, OT* __restrict__ C,
                          int M, int N, int K, int relu) {
    __shared__ float As[TS][TS + 1];
    __shared__ float Ws[TS][TS + 1];
    int tx = threadIdx.x, ty = threadIdx.y;
    int col = blockIdx.x * TS + tx;
    int row = blockIdx.y * TS + ty;
    float acc = 0.f;
    for (int k0 = 0; k0 < K; k0 += TS) {
        As[ty][tx] = (row < M) ? A[(size_t)row * K + k0 + tx] : 0.f;
        Ws[ty][tx] = (col < N) ? W[(size_t)(k0 + ty) * N + col] : 0.f;
        __syncthreads();
#pragma unroll
        for (int kk = 0; kk < TS; kk++) acc += As[ty][kk] * Ws[kk][tx];
        __syncthreads();
    }
    if (row < M && col < N) {
        acc += bias[col];
        if (relu) acc = fmaxf(acc, 0.f);
        stval(C + (size_t)row * N + col, acc);
    }
}

// ---------------- elementwise add ----------------
__global__ void add2(const float* __restrict__ a, const float* __restrict__ b,
                     float* __restrict__ o, int n) {
    int i = blockIdx.x * blockDim.x + threadIdx.x;
    if (i < n) o[i] = a[i] + b[i];
}

__global__ void fillmark(float* o, int n, float v) {
    int i = blockIdx.x * blockDim.x + threadIdx.x;
    if (i < n) o[i] = v;
}

// ---------------- residual + layernorm (one block per row of 256) -----------
template <typename OT>
__global__ void ln_res(const float* __restrict__ a, const float* __restrict__ b,
                       const float* __restrict__ g, const float* __restrict__ be,
                       OT* __restrict__ o) {
    int row = blockIdx.x;
    int t = threadIdx.x;
    float x = a[(size_t)row * DD + t] + b[(size_t)row * DD + t];
    __shared__ float red[DD];
    red[t] = x;
    __syncthreads();
    for (int s = 128; s > 0; s >>= 1) {
        if (t < s) red[t] += red[t + s];
        __syncthreads();
    }
    float m = red[0] * (1.f / DD);
    __syncthreads();
    float d0 = x - m;
    red[t] = d0 * d0;
    __syncthreads();
    for (int s = 128; s > 0; s >>= 1) {
        if (t < s) red[t] += red[t + s];
        __syncthreads();
    }
    float v = red[0] * (1.f / DD);
    float y = d0 * rsqrtf(v + 1e-5f) * g[t] + be[t];
    stval(o + (size_t)row * DD + t, y);
}

// ---------------- self-attention: one block per (b,h,q) ---------------------
__global__ void sa_attn(const float* __restrict__ Q, const float* __restrict__ K,
                        const float* __restrict__ V, float* __restrict__ O) {
    int blk = blockIdx.x;
    int q = blk % NQQ;
    int bh = blk / NQQ;
    int h = bh % NH;
    int b = bh / NH;
    int t = threadIdx.x;
    __shared__ float qv[HDIM];
    __shared__ float s[NQQ];
    __shared__ float red[256];
    __shared__ float part[256];
    const float* qrow = Q + ((size_t)(b * NQQ + q)) * DD + h * HDIM;
    if (t < HDIM) qv[t] = qrow[t];
    __syncthreads();
    const float scale = 0.17677669529663687f;  // 32^-0.5
    for (int k = t; k < NQQ; k += 256) {
        const float* krow = K + ((size_t)(b * NQQ + k)) * DD + h * HDIM;
        float acc = 0.f;
#pragma unroll
        for (int d = 0; d < HDIM; d++) acc += qv[d] * krow[d];
        s[k] = acc * scale;
    }
    __syncthreads();
    float lm = -1e30f;
    for (int k = t; k < NQQ; k += 256) lm = fmaxf(lm, s[k]);
    red[t] = lm;
    __syncthreads();
    for (int st = 128; st > 0; st >>= 1) {
        if (t < st) red[t] = fmaxf(red[t], red[t + st]);
        __syncthreads();
    }
    float mx = red[0];
    __syncthreads();
    float ls = 0.f;
    for (int k = t; k < NQQ; k += 256) {
        float e = expf(s[k] - mx);
        s[k] = e;
        ls += e;
    }
    red[t] = ls;
    __syncthreads();
    for (int st = 128; st > 0; st >>= 1) {
        if (t < st) red[t] += red[t + st];
        __syncthreads();
    }
    float inv = 1.f / red[0];
    int d = t & 31, c = t >> 5;
    float acc = 0.f;
    for (int k = c; k < NQQ; k += 8)
        acc += s[k] * V[((size_t)(b * NQQ + k)) * DD + h * HDIM + d];
    part[t] = acc;
    __syncthreads();
    if (t < HDIM) {
        float sum = 0.f;
#pragma unroll
        for (int c2 = 0; c2 < 8; c2++) sum += part[c2 * 32 + t];
        O[((size_t)(b * NQQ + q)) * DD + h * HDIM + t] = sum * inv;
    }
}

// ---------------- msdeform sampling: one block per (b,q), 8 heads x 32 dims --
__device__ inline float tapb(const __hip_bfloat16* __restrict__ vbase, int xi, int yi, int Wl, int Hl) {
    if (xi < 0 || xi >= Wl || yi < 0 || yi >= Hl) return 0.f;
    return __bfloat162float(vbase[(size_t)(yi * Wl + xi) * DD]);
}

__global__ void msdeform(const __hip_bfloat16* __restrict__ val, const float* __restrict__ off,
                         const float* __restrict__ awl, const float* __restrict__ ref,
                         float* __restrict__ out) {
    int blk = blockIdx.x;  // b*NQQ + q
    int b = blk / NQQ;
    int qi = blk % NQQ;
    int t = threadIdx.x;
    int h = t >> 5, d = t & 31;
    const int Hs[4] = {128, 64, 32, 16};
    const int Wsz[4] = {128, 64, 32, 16};
    const int stt[4] = {0, 16384, 20480, 21504};
    const float* offrow = off + (size_t)blk * 256 + h * 32;
    const float* awrow = awl + (size_t)blk * 128 + h * 16;
    float mx = -1e30f;
#pragma unroll
    for (int i = 0; i < 16; i++) mx = fmaxf(mx, awrow[i]);
    float ssum = 0.f;
    float aw[16];
#pragma unroll
    for (int i = 0; i < 16; i++) {
        aw[i] = expf(awrow[i] - mx);
        ssum += aw[i];
    }
    float inv = 1.f / ssum;
    float acc = 0.f;
#pragma unroll
    for (int l = 0; l < LV; l++) {
        const float* rp = ref + ((size_t)(b * NQQ + qi) * LV + l) * 4;
        float cx = rp[0], cy = rp[1], rw = rp[2], rh = rp[3];
        int Wl = Wsz[l], Hl = Hs[l];
        const __hip_bfloat16* vbase = val + ((size_t)b * SS + stt[l]) * DD + h * HDIM + d;
#pragma unroll
        for (int p = 0; p < NP; p++) {
            float ox = offrow[l * 8 + p * 2 + 0], oy = offrow[l * 8 + p * 2 + 1];
            float lx = cx + ox * (1.0f / NP) * rw * 0.5f;
            float ly = cy + oy * (1.0f / NP) * rh * 0.5f;
            float x = lx * Wl - 0.5f, y = ly * Hl - 0.5f;
            float x0f = floorf(x), y0f = floorf(y);
            float dx = x - x0f, dy = y - y0f;
            int x0 = (int)x0f, y0 = (int)y0f;
            float w00 = (1 - dx) * (1 - dy), w10 = dx * (1 - dy);
            float w01 = (1 - dx) * dy, w11 = dx * dy;
            float sv = w00 * tapb(vbase, x0, y0, Wl, Hl) + w10 * tapb(vbase, x0 + 1, y0, Wl, Hl) +
                       w01 * tapb(vbase, x0, y0 + 1, Wl, Hl) + w11 * tapb(vbase, x0 + 1, y0 + 1, Wl, Hl);
            acc += aw[l * 4 + p] * inv * sv;
        }
    }
    out[(size_t)blk * DD + h * HDIM + d] = acc;
}

// ---------------- launch ----------------
extern "C" void kernel_launch(void* const* d_in, const int* in_sizes, int n_in,
                              void* d_out, int out_size, void* d_ws, size_t ws_size,
                              hipStream_t stream) {
    const float* query       = (const float*)d_in[0];
    const float* query_pos   = (const float*)d_in[1];
    const float* refpts      = (const float*)d_in[2];
    const float* input_flat  = (const float*)d_in[3];
    const float* sa_in_w     = (const float*)d_in[6];
    const float* sa_in_b     = (const float*)d_in[7];
    const float* sa_out_w    = (const float*)d_in[8];
    const float* sa_out_b    = (const float*)d_in[9];
    const float* norm1_g     = (const float*)d_in[10];
    const float* norm1_b     = (const float*)d_in[11];
    const float* value_w     = (const float*)d_in[12];
    const float* value_b     = (const float*)d_in[13];
    const float* off_w       = (const float*)d_in[14];
    const float* off_b       = (const float*)d_in[15];
    const float* aw_w        = (const float*)d_in[16];
    const float* aw_b        = (const float*)d_in[17];
    const float* ca_out_w    = (const float*)d_in[18];
    const float* ca_out_b    = (const float*)d_in[19];
    const float* norm2_g     = (const float*)d_in[20];
    const float* norm2_b     = (const float*)d_in[21];
    const float* lin1_w      = (const float*)d_in[22];
    const float* lin1_b      = (const float*)d_in[23];
    const float* lin2_w      = (const float*)d_in[24];
    const float* lin2_b      = (const float*)d_in[25];
    const float* norm3_g     = (const float*)d_in[26];
    const float* norm3_b     = (const float*)d_in[27];
    float* out = (float*)d_out;   // reference output dtype is float32

    const int M = BB * NQQ;          // 3600
    const int NE = M * DD;           // 921600

    // workspace layout: 4 f32 slots + big region (bf16 value / f32 ffn1)
    const size_t slotBytes = (size_t)NE * 4;                 // 3.686 MB each
    const size_t bigBytes  = (size_t)BB * SS * DD * 2;       // 44.56 MB (bf16 value)
    const size_t needBytes = 4 * slotBytes + bigBytes;       // 59.3 MB
    if (ws_size < needBytes) {
        float mark = 1000.0f + (float)(ws_size >> 20);
        fillmark<<<(out_size + 255) / 256, 256, 0, stream>>>(out, out_size, mark);
        return;
    }

    char* wsb = (char*)d_ws;
    float* sa_ = (float*)(wsb);
    float* sb_ = (float*)(wsb + slotBytes);
    float* sc_ = (float*)(wsb + 2 * slotBytes);
    float* sd_ = (float*)(wsb + 3 * slotBytes);
    __hip_bfloat16* vbig = (__hip_bfloat16*)(wsb + 4 * slotBytes);
    float* ffn1 = (float*)(wsb + 4 * slotBytes);             // reused after value dies

    dim3 blk16(TS, TS);
    dim3 g_dd((DD + TS - 1) / TS, (M + TS - 1) / TS);        // (16,225)
    dim3 g_val((DD + TS - 1) / TS, (BB * SS + TS - 1) / TS); // (16,5440)
    dim3 g_aw((128 + TS - 1) / TS, (M + TS - 1) / TS);       // (8,225)
    dim3 g_ffn1((DFF + TS - 1) / TS, (M + TS - 1) / TS);     // (128,225)

    // 1. qk = query + query_pos  -> slot a
    add2<<<(NE + 255) / 256, 256, 0, stream>>>(query, query_pos, sa_, NE);
    // 2. Q,K,V projections -> b,c,d
    gemm_bias<float><<<g_dd, blk16, 0, stream>>>(sa_, sa_in_w,            sa_in_b,       sb_, M, DD, DD, 0);
    gemm_bias<float><<<g_dd, blk16, 0, stream>>>(sa_, sa_in_w + 65536,    sa_in_b + 256, sc_, M, DD, DD, 0);
    gemm_bias<float><<<g_dd, blk16, 0, stream>>>(query, sa_in_w + 131072, sa_in_b + 512, sd_, M, DD, DD, 0);
    // 3. attention -> slot a (qk dead)
    sa_attn<<<BB * NH * NQQ, 256, 0, stream>>>(sb_, sc_, sd_, sa_);
    // 4. sa projection -> slot c
    gemm_bias<float><<<g_dd, blk16, 0, stream>>>(sa_, sa_out_w, sa_out_b, sc_, M, DD, DD, 0);
    // 5. x1 = LN(query + sa_proj) -> slot d
    ln_res<float><<<M, DD, 0, stream>>>(query, sc_, norm1_g, norm1_b, sd_);
    // 6. q2 = x1 + query_pos -> slot a
    add2<<<(NE + 255) / 256, 256, 0, stream>>>(sd_, query_pos, sa_, NE);
    // 7. value projection -> big (bf16)
    gemm_bias<__hip_bfloat16><<<g_val, blk16, 0, stream>>>(input_flat, value_w, value_b, vbig, BB * SS, DD, DD, 0);
    // 8. offsets -> slot b ; 9. attention-weight logits -> slot c
    gemm_bias<float><<<g_dd, blk16, 0, stream>>>(sa_, off_w, off_b, sb_, M, DD, DD, 0);
    gemm_bias<float><<<g_aw, blk16, 0, stream>>>(sa_, aw_w, aw_b, sc_, M, 128, DD, 0);
    // 10. deformable sampling -> slot a (q2 dead)
    msdeform<<<BB * NQQ, 256, 0, stream>>>(vbig, sb_, sc_, refpts, sa_);
    // 11. ca projection -> slot c
    gemm_bias<float><<<g_dd, blk16, 0, stream>>>(sa_, ca_out_w, ca_out_b, sc_, M, DD, DD, 0);
    // 12. x2 = LN(x1 + ca) -> slot b
    ln_res<float><<<M, DD, 0, stream>>>(sd_, sc_, norm2_g, norm2_b, sb_);
    // 13. ffn1 = relu(x2 @ lin1) -> big region (value dead)
    gemm_bias<float><<<g_ffn1, blk16, 0, stream>>>(sb_, lin1_w, lin1_b, ffn1, M, DFF, DD, 1);
    // 14. ffn2 -> slot a
    gemm_bias<float><<<g_dd, blk16, 0, stream>>>(ffn1, lin2_w, lin2_b, sa_, M, DD, DFF, 0);
    // 15. out = LN(x2 + ffn2) -> f32 d_out
    ln_res<float><<<M, DD, 0, stream>>>(sb_, sa_, norm3_g, norm3_b, out);
}

// Round 4
// 854.772 us; speedup vs baseline: 2.5515x; 2.5515x over previous
//
#include <hip/hip_runtime.h>
#include <hip/hip_bf16.h>

#define DD   256
#define NH   8
#define HDIM 32
#define LV   4
#define NP   4
#define DFF  2048
#define BB   4
#define NQQ  900
#define SS   21760

typedef __bf16 bf16x8 __attribute__((ext_vector_type(8)));
typedef float  f32x4  __attribute__((ext_vector_type(4)));

__device__ inline void stval(float* p, float v) { *p = v; }
__device__ inline void stval(__bf16* p, float v) { *p = (__bf16)v; }

// ============ weight transpose+convert: Wt[N][K] bf16 <- W[K][N] f32 =========
__global__ void transp_cvt(const float* __restrict__ W, __bf16* __restrict__ Wt,
                           int K, int N) {
    __shared__ float t[32][33];
    int nb = blockIdx.x * 32, kb = blockIdx.y * 32;
    for (int i = threadIdx.y; i < 32; i += 8)
        t[i][threadIdx.x] = W[(size_t)(kb + i) * N + nb + threadIdx.x];
    __syncthreads();
    for (int i = threadIdx.y; i < 32; i += 8)
        Wt[(size_t)(nb + i) * K + kb + threadIdx.x] = (__bf16)t[threadIdx.x][i];
}

// ============ MFMA GEMM: C[M][N] = A[M][K] @ Wt[N][K]^T + bias ==============
// BM=BN=BK=64, 256 threads (4 waves, 2x2), 16x16x32 bf16 MFMA, swizzled LDS.
#define BM 64
#define BN 64
#define BKK 64

template <typename AT, typename OT, int RELU>
__global__ __launch_bounds__(256) void mfma_gemm(
    const AT* __restrict__ A, const __bf16* __restrict__ Wt,
    const float* __restrict__ bias, OT* __restrict__ C,
    int M, int N, int K) {
    int tid = threadIdx.x;
    int lane = tid & 63;
    int wave = tid >> 6;
    int wr = wave >> 1, wc = wave & 1;
    int m0 = blockIdx.y * BM;
    int n0 = blockIdx.x * BN;

    __shared__ __attribute__((aligned(16))) __bf16 As[BM * BKK];
    __shared__ __attribute__((aligned(16))) __bf16 Bs[BN * BKK];

    f32x4 acc[2][2] = {};

    int srow = tid >> 2;   // 0..63 (row within tile)
    int sq = tid & 3;      // k-quarter (16 elems)
    int u0 = sq << 1;      // first 16B unit
    int p0 = (u0 ^ (srow & 7)) * 8;        // elem offsets (swizzled)
    int p1 = ((u0 + 1) ^ (srow & 7)) * 8;
    int fr = lane & 15, gq = lane >> 4;

    for (int k0 = 0; k0 < K; k0 += BKK) {
        // ---- stage A (f32 or bf16 source -> bf16 LDS) ----
        {
            int gm = m0 + srow;
            bf16x8 v0 = {}, v1 = {};
            if (gm < M) {
                if constexpr (sizeof(AT) == 4) {
                    const float* ap = (const float*)A + (size_t)gm * K + k0 + sq * 16;
                    f32x4 f0 = *(const f32x4*)(ap + 0);
                    f32x4 f1 = *(const f32x4*)(ap + 4);
                    f32x4 f2 = *(const f32x4*)(ap + 8);
                    f32x4 f3 = *(const f32x4*)(ap + 12);
#pragma unroll
                    for (int e = 0; e < 4; e++) {
                        v0[e] = (__bf16)f0[e]; v0[e + 4] = (__bf16)f1[e];
                        v1[e] = (__bf16)f2[e]; v1[e + 4] = (__bf16)f3[e];
                    }
                } else {
                    const __bf16* ap = (const __bf16*)A + (size_t)gm * K + k0 + sq * 16;
                    v0 = *(const bf16x8*)(ap);
                    v1 = *(const bf16x8*)(ap + 8);
                }
            }
            *(bf16x8*)(&As[srow * 64 + p0]) = v0;
            *(bf16x8*)(&As[srow * 64 + p1]) = v1;
        }
        // ---- stage B (Wt bf16, rows are output-cols) ----
        {
            int gn = n0 + srow;
            const __bf16* bp = Wt + (size_t)gn * K + k0 + sq * 16;
            bf16x8 w0 = *(const bf16x8*)(bp);
            bf16x8 w1 = *(const bf16x8*)(bp + 8);
            *(bf16x8*)(&Bs[srow * 64 + p0]) = w0;
            *(bf16x8*)(&Bs[srow * 64 + p1]) = w1;
        }
        __syncthreads();
#pragma unroll
        for (int ks = 0; ks < 2; ks++) {
            bf16x8 a[2], b[2];
#pragma unroll
            for (int i = 0; i < 2; i++) {
                int ma = wr * 32 + i * 16 + fr;
                a[i] = *(const bf16x8*)(&As[ma * 64 + ((ks * 4 + gq) ^ (ma & 7)) * 8]);
                int nb = wc * 32 + i * 16 + fr;
                b[i] = *(const bf16x8*)(&Bs[nb * 64 + ((ks * 4 + gq) ^ (nb & 7)) * 8]);
            }
#pragma unroll
            for (int i = 0; i < 2; i++)
#pragma unroll
                for (int j = 0; j < 2; j++)
                    acc[i][j] = __builtin_amdgcn_mfma_f32_16x16x32_bf16(a[i], b[j], acc[i][j], 0, 0, 0);
        }
        __syncthreads();
    }
    // ---- epilogue: D col=lane&15, row=(lane>>4)*4+reg ----
    int orow = gq * 4;
#pragma unroll
    for (int i = 0; i < 2; i++)
#pragma unroll
        for (int j = 0; j < 2; j++) {
            int gn = n0 + wc * 32 + j * 16 + fr;
            float bv = bias[gn];
#pragma unroll
            for (int r = 0; r < 4; r++) {
                int gm = m0 + wr * 32 + i * 16 + orow + r;
                if (gm < M) {
                    float v = acc[i][j][r] + bv;
                    if (RELU) v = fmaxf(v, 0.f);
                    stval(C + (size_t)gm * N + gn, v);
                }
            }
        }
}

// ---------------- elementwise add ----------------
__global__ void add2(const float* __restrict__ a, const float* __restrict__ b,
                     float* __restrict__ o, int n) {
    int i = blockIdx.x * blockDim.x + threadIdx.x;
    if (i < n) o[i] = a[i] + b[i];
}

__global__ void fillmark(float* o, int n, float v) {
    int i = blockIdx.x * blockDim.x + threadIdx.x;
    if (i < n) o[i] = v;
}

// ---------------- residual + layernorm ----------------
__global__ void ln_res(const float* a, const float* b,
                       const float* g, const float* be, float* o) {
    int row = blockIdx.x;
    int t = threadIdx.x;
    float x = a[(size_t)row * DD + t] + b[(size_t)row * DD + t];
    __shared__ float red[DD];
    red[t] = x;
    __syncthreads();
    for (int s = 128; s > 0; s >>= 1) {
        if (t < s) red[t] += red[t + s];
        __syncthreads();
    }
    float m = red[0] * (1.f / DD);
    __syncthreads();
    float d0 = x - m;
    red[t] = d0 * d0;
    __syncthreads();
    for (int s = 128; s > 0; s >>= 1) {
        if (t < s) red[t] += red[t + s];
        __syncthreads();
    }
    float v = red[0] * (1.f / DD);
    o[(size_t)row * DD + t] = d0 * rsqrtf(v + 1e-5f) * g[t] + be[t];
}

// ---------------- self-attention (bf16 Q,K,V) ----------------
__global__ void sa_attn(const __bf16* __restrict__ Q, const __bf16* __restrict__ K,
                        const __bf16* __restrict__ V, float* __restrict__ O) {
    int blk = blockIdx.x;
    int q = blk % NQQ;
    int bh = blk / NQQ;
    int h = bh % NH;
    int b = bh / NH;
    int t = threadIdx.x;
    __shared__ float qv[HDIM];
    __shared__ float s[NQQ];
    __shared__ float red[256];
    __shared__ float part[256];
    const __bf16* qrow = Q + ((size_t)(b * NQQ + q)) * DD + h * HDIM;
    if (t < HDIM) qv[t] = (float)qrow[t];
    __syncthreads();
    const float scale = 0.17677669529663687f;
    for (int k = t; k < NQQ; k += 256) {
        const __bf16* krow = K + ((size_t)(b * NQQ + k)) * DD + h * HDIM;
        float acc = 0.f;
#pragma unroll
        for (int d = 0; d < HDIM; d++) acc += qv[d] * (float)krow[d];
        s[k] = acc * scale;
    }
    __syncthreads();
    float lm = -1e30f;
    for (int k = t; k < NQQ; k += 256) lm = fmaxf(lm, s[k]);
    red[t] = lm;
    __syncthreads();
    for (int st = 128; st > 0; st >>= 1) {
        if (t < st) red[t] = fmaxf(red[t], red[t + st]);
        __syncthreads();
    }
    float mx = red[0];
    __syncthreads();
    float ls = 0.f;
    for (int k = t; k < NQQ; k += 256) {
        float e = expf(s[k] - mx);
        s[k] = e;
        ls += e;
    }
    red[t] = ls;
    __syncthreads();
    for (int st = 128; st > 0; st >>= 1) {
        if (t < st) red[t] += red[t + st];
        __syncthreads();
    }
    float inv = 1.f / red[0];
    int d = t & 31, c = t >> 5;
    float acc = 0.f;
    for (int k = c; k < NQQ; k += 8)
        acc += s[k] * (float)V[((size_t)(b * NQQ + k)) * DD + h * HDIM + d];
    part[t] = acc;
    __syncthreads();
    if (t < HDIM) {
        float sum = 0.f;
#pragma unroll
        for (int c2 = 0; c2 < 8; c2++) sum += part[c2 * 32 + t];
        O[((size_t)(b * NQQ + q)) * DD + h * HDIM + t] = sum * inv;
    }
}

// ---------------- msdeform sampling (bf16 value/off/aw) ----------------
__device__ inline float tapb(const __bf16* __restrict__ vbase, int xi, int yi, int Wl, int Hl) {
    if (xi < 0 || xi >= Wl || yi < 0 || yi >= Hl) return 0.f;
    return (float)vbase[(size_t)(yi * Wl + xi) * DD];
}

__global__ void msdeform(const __bf16* __restrict__ val, const __bf16* __restrict__ off,
                         const __bf16* __restrict__ awl, const float* __restrict__ ref,
                         float* __restrict__ out) {
    int blk = blockIdx.x;
    int b = blk / NQQ;
    int qi = blk % NQQ;
    int t = threadIdx.x;
    int h = t >> 5, d = t & 31;
    const int Hs[4] = {128, 64, 32, 16};
    const int Wsz[4] = {128, 64, 32, 16};
    const int stt[4] = {0, 16384, 20480, 21504};
    const __bf16* offrow = off + (size_t)blk * 256 + h * 32;
    const __bf16* awrow = awl + (size_t)blk * 128 + h * 16;
    float mx = -1e30f;
#pragma unroll
    for (int i = 0; i < 16; i++) mx = fmaxf(mx, (float)awrow[i]);
    float ssum = 0.f;
    float aw[16];
#pragma unroll
    for (int i = 0; i < 16; i++) {
        aw[i] = expf((float)awrow[i] - mx);
        ssum += aw[i];
    }
    float inv = 1.f / ssum;
    float acc = 0.f;
#pragma unroll
    for (int l = 0; l < LV; l++) {
        const float* rp = ref + ((size_t)(b * NQQ + qi) * LV + l) * 4;
        float cx = rp[0], cy = rp[1], rw = rp[2], rh = rp[3];
        int Wl = Wsz[l], Hl = Hs[l];
        const __bf16* vbase = val + ((size_t)b * SS + stt[l]) * DD + h * HDIM + d;
#pragma unroll
        for (int p = 0; p < NP; p++) {
            float ox = (float)offrow[l * 8 + p * 2 + 0], oy = (float)offrow[l * 8 + p * 2 + 1];
            float lx = cx + ox * (1.0f / NP) * rw * 0.5f;
            float ly = cy + oy * (1.0f / NP) * rh * 0.5f;
            float x = lx * Wl - 0.5f, y = ly * Hl - 0.5f;
            float x0f = floorf(x), y0f = floorf(y);
            float dx = x - x0f, dy = y - y0f;
            int x0 = (int)x0f, y0 = (int)y0f;
            float w00 = (1 - dx) * (1 - dy), w10 = dx * (1 - dy);
            float w01 = (1 - dx) * dy, w11 = dx * dy;
            float sv = w00 * tapb(vbase, x0, y0, Wl, Hl) + w10 * tapb(vbase, x0 + 1, y0, Wl, Hl) +
                       w01 * tapb(vbase, x0, y0 + 1, Wl, Hl) + w11 * tapb(vbase, x0 + 1, y0 + 1, Wl, Hl);
            acc += aw[l * 4 + p] * inv * sv;
        }
    }
    out[(size_t)blk * DD + h * HDIM + d] = acc;
}

// ---------------- launch ----------------
extern "C" void kernel_launch(void* const* d_in, const int* in_sizes, int n_in,
                              void* d_out, int out_size, void* d_ws, size_t ws_size,
                              hipStream_t stream) {
    const float* query      = (const float*)d_in[0];
    const float* query_pos  = (const float*)d_in[1];
    const float* refpts     = (const float*)d_in[2];
    const float* input_flat = (const float*)d_in[3];
    const float* sa_in_w    = (const float*)d_in[6];
    const float* sa_in_b    = (const float*)d_in[7];
    const float* sa_out_w   = (const float*)d_in[8];
    const float* sa_out_b   = (const float*)d_in[9];
    const float* norm1_g    = (const float*)d_in[10];
    const float* norm1_b    = (const float*)d_in[11];
    const float* value_w    = (const float*)d_in[12];
    const float* value_b    = (const float*)d_in[13];
    const float* off_w      = (const float*)d_in[14];
    const float* off_b      = (const float*)d_in[15];
    const float* aw_w       = (const float*)d_in[16];
    const float* aw_b       = (const float*)d_in[17];
    const float* ca_out_w   = (const float*)d_in[18];
    const float* ca_out_b   = (const float*)d_in[19];
    const float* norm2_g    = (const float*)d_in[20];
    const float* norm2_b    = (const float*)d_in[21];
    const float* lin1_w     = (const float*)d_in[22];
    const float* lin1_b     = (const float*)d_in[23];
    const float* lin2_w     = (const float*)d_in[24];
    const float* lin2_b     = (const float*)d_in[25];
    const float* norm3_g    = (const float*)d_in[26];
    const float* norm3_b    = (const float*)d_in[27];
    float* out = (float*)d_out;

    const int M = BB * NQQ;              // 3600
    const int NE = M * DD;               // 921600
    const size_t slotBytes = (size_t)NE * 4;            // 3,686,400
    const size_t wElems = 6 * 65536 + 32768 + 65536 + 2 * 524288;  // 1,540,096
    const size_t wBytes = wElems * 2;                   // 3,080,192
    const size_t bigBytes = (size_t)BB * SS * DD * 2;   // 44,564,480
    const size_t needBytes = 3 * slotBytes + wBytes + bigBytes;  // 58,703,872
    if (ws_size < needBytes) {
        float mark = 1000.0f + (float)(ws_size >> 20);
        fillmark<<<(out_size + 255) / 256, 256, 0, stream>>>(out, out_size, mark);
        return;
    }

    char* wsb = (char*)d_ws;
    float* s0 = (float*)(wsb);
    float* s1 = (float*)(wsb + slotBytes);
    float* s2 = (float*)(wsb + 2 * slotBytes);
    __bf16* wb = (__bf16*)(wsb + 3 * slotBytes);
    __bf16* vbig = (__bf16*)(wsb + 3 * slotBytes + wBytes);

    // transposed-weight slots (elem offsets in wb)
    __bf16* wt_q   = wb;
    __bf16* wt_k   = wb + 65536;
    __bf16* wt_v   = wb + 131072;
    __bf16* wt_sa  = wb + 196608;
    __bf16* wt_val = wb + 262144;
    __bf16* wt_off = wb + 327680;
    __bf16* wt_aw  = wb + 393216;
    __bf16* wt_ca  = wb + 425984;
    __bf16* wt_l1  = wb + 491520;
    __bf16* wt_l2  = wb + 1015808;

    dim3 tb(32, 8);
    transp_cvt<<<dim3(8, 8),  tb, 0, stream>>>(sa_in_w,          wt_q,  DD, DD);
    transp_cvt<<<dim3(8, 8),  tb, 0, stream>>>(sa_in_w + 65536,  wt_k,  DD, DD);
    transp_cvt<<<dim3(8, 8),  tb, 0, stream>>>(sa_in_w + 131072, wt_v,  DD, DD);
    transp_cvt<<<dim3(8, 8),  tb, 0, stream>>>(sa_out_w,         wt_sa, DD, DD);
    transp_cvt<<<dim3(8, 8),  tb, 0, stream>>>(value_w,          wt_val, DD, DD);
    transp_cvt<<<dim3(8, 8),  tb, 0, stream>>>(off_w,            wt_off, DD, DD);
    transp_cvt<<<dim3(4, 8),  tb, 0, stream>>>(aw_w,             wt_aw, DD, 128);
    transp_cvt<<<dim3(8, 8),  tb, 0, stream>>>(ca_out_w,         wt_ca, DD, DD);
    transp_cvt<<<dim3(64, 8), tb, 0, stream>>>(lin1_w,           wt_l1, DD, DFF);
    transp_cvt<<<dim3(8, 64), tb, 0, stream>>>(lin2_w,           wt_l2, DFF, DD);

    __bf16* Qp = (__bf16*)s1;
    __bf16* Kp = (__bf16*)s1 + NE;
    __bf16* Vp = (__bf16*)s2;
    __bf16* offb = (__bf16*)s1;
    __bf16* awb = (__bf16*)s1 + NE;

    const int mt = (M + BM - 1) / BM;    // 57
    const int mtv = (BB * SS) / BM;      // 1360

    // 1. qk = query + query_pos -> s0
    add2<<<(NE + 255) / 256, 256, 0, stream>>>(query, query_pos, s0, NE);
    // 2-4. Q,K,V projections (bf16 out)
    mfma_gemm<float, __bf16, 0><<<dim3(4, mt), 256, 0, stream>>>(s0, wt_q, sa_in_b, Qp, M, DD, DD);
    mfma_gemm<float, __bf16, 0><<<dim3(4, mt), 256, 0, stream>>>(s0, wt_k, sa_in_b + 256, Kp, M, DD, DD);
    mfma_gemm<float, __bf16, 0><<<dim3(4, mt), 256, 0, stream>>>(query, wt_v, sa_in_b + 512, Vp, M, DD, DD);
    // 5. attention -> s0
    sa_attn<<<BB * NH * NQQ, 256, 0, stream>>>(Qp, Kp, Vp, s0);
    // 6. sa projection -> s1 (f32)
    mfma_gemm<float, float, 0><<<dim3(4, mt), 256, 0, stream>>>(s0, wt_sa, sa_out_b, s1, M, DD, DD);
    // 7. x1 = LN(query + s1) -> s2
    ln_res<<<M, DD, 0, stream>>>(query, s1, norm1_g, norm1_b, s2);
    // 8. q2 = x1 + query_pos -> s0
    add2<<<(NE + 255) / 256, 256, 0, stream>>>(s2, query_pos, s0, NE);
    // 9. value projection -> vbig (bf16)
    mfma_gemm<float, __bf16, 0><<<dim3(4, mtv), 256, 0, stream>>>(input_flat, wt_val, value_b, vbig, BB * SS, DD, DD);
    // 10-11. offsets (bf16) + aw logits (bf16)
    mfma_gemm<float, __bf16, 0><<<dim3(4, mt), 256, 0, stream>>>(s0, wt_off, off_b, offb, M, DD, DD);
    mfma_gemm<float, __bf16, 0><<<dim3(2, mt), 256, 0, stream>>>(s0, wt_aw, aw_b, awb, M, 128, DD);
    // 12. deformable sampling -> s0
    msdeform<<<BB * NQQ, 256, 0, stream>>>(vbig, offb, awb, refpts, s0);
    // 13. ca projection -> s1 (f32)
    mfma_gemm<float, float, 0><<<dim3(4, mt), 256, 0, stream>>>(s0, wt_ca, ca_out_b, s1, M, DD, DD);
    // 14. x2 = LN(x1 + ca) -> s1
    ln_res<<<M, DD, 0, stream>>>(s2, s1, norm2_g, norm2_b, s1);
    // 15. ffn1 = relu(x2 @ lin1) -> vbig (bf16)
    mfma_gemm<float, __bf16, 1><<<dim3(32, mt), 256, 0, stream>>>(s1, wt_l1, lin1_b, vbig, M, DFF, DD);
    // 16. ffn2 -> s0 (f32)
    mfma_gemm<__bf16, float, 0><<<dim3(4, mt), 256, 0, stream>>>(vbig, wt_l2, lin2_b, s0, M, DD, DFF);
    // 17. out = LN(x2 + ffn2) -> d_out
    ln_res<<<M, DD, 0, stream>>>(s1, s0, norm3_g, norm3_b, out);
}

// Round 5
// 361.117 us; speedup vs baseline: 6.0394x; 2.3670x over previous
//
#include <hip/hip_runtime.h>
#include <hip/hip_bf16.h>

#define DD   256
#define NH   8
#define HDIM 32
#define LV   4
#define NP   4
#define DFF  2048
#define BB   4
#define NQQ  900
#define SS   21760

typedef __bf16 bf16x8 __attribute__((ext_vector_type(8)));
typedef float  f32x4  __attribute__((ext_vector_type(4)));

__device__ inline void stval(float* p, float v) { *p = v; }
__device__ inline void stval(__bf16* p, float v) { *p = (__bf16)v; }

// ============ weight transpose+convert: Wt[N][K] bf16 <- W[K][N] f32 =========
__global__ void transp_cvt(const float* __restrict__ W, __bf16* __restrict__ Wt,
                           int K, int N) {
    __shared__ float t[32][33];
    int nb = blockIdx.x * 32, kb = blockIdx.y * 32;
    for (int i = threadIdx.y; i < 32; i += 8)
        t[i][threadIdx.x] = W[(size_t)(kb + i) * N + nb + threadIdx.x];
    __syncthreads();
    for (int i = threadIdx.y; i < 32; i += 8)
        Wt[(size_t)(nb + i) * K + kb + threadIdx.x] = (__bf16)t[threadIdx.x][i];
}

// ============ MFMA GEMM: C[M][N] = A[M][K] @ Wt[N][K]^T + bias ==============
#define BM 64
#define BN 64
#define BKK 64

template <typename AT, typename OT, int RELU>
__global__ __launch_bounds__(256) void mfma_gemm(
    const AT* __restrict__ A, const __bf16* __restrict__ Wt,
    const float* __restrict__ bias, OT* __restrict__ C,
    int M, int N, int K) {
    int tid = threadIdx.x;
    int lane = tid & 63;
    int wave = tid >> 6;
    int wr = wave >> 1, wc = wave & 1;
    int m0 = blockIdx.y * BM;
    int n0 = blockIdx.x * BN;

    __shared__ __attribute__((aligned(16))) __bf16 As[BM * BKK];
    __shared__ __attribute__((aligned(16))) __bf16 Bs[BN * BKK];

    f32x4 acc[2][2] = {};

    int srow = tid >> 2;
    int sq = tid & 3;
    int u0 = sq << 1;
    int p0 = (u0 ^ (srow & 7)) * 8;
    int p1 = ((u0 + 1) ^ (srow & 7)) * 8;
    int fr = lane & 15, gq = lane >> 4;

    for (int k0 = 0; k0 < K; k0 += BKK) {
        {
            int gm = m0 + srow;
            bf16x8 v0 = {}, v1 = {};
            if (gm < M) {
                if constexpr (sizeof(AT) == 4) {
                    const float* ap = (const float*)A + (size_t)gm * K + k0 + sq * 16;
                    f32x4 f0 = *(const f32x4*)(ap + 0);
                    f32x4 f1 = *(const f32x4*)(ap + 4);
                    f32x4 f2 = *(const f32x4*)(ap + 8);
                    f32x4 f3 = *(const f32x4*)(ap + 12);
#pragma unroll
                    for (int e = 0; e < 4; e++) {
                        v0[e] = (__bf16)f0[e]; v0[e + 4] = (__bf16)f1[e];
                        v1[e] = (__bf16)f2[e]; v1[e + 4] = (__bf16)f3[e];
                    }
                } else {
                    const __bf16* ap = (const __bf16*)A + (size_t)gm * K + k0 + sq * 16;
                    v0 = *(const bf16x8*)(ap);
                    v1 = *(const bf16x8*)(ap + 8);
                }
            }
            *(bf16x8*)(&As[srow * 64 + p0]) = v0;
            *(bf16x8*)(&As[srow * 64 + p1]) = v1;
        }
        {
            int gn = n0 + srow;
            const __bf16* bp = Wt + (size_t)gn * K + k0 + sq * 16;
            bf16x8 w0 = *(const bf16x8*)(bp);
            bf16x8 w1 = *(const bf16x8*)(bp + 8);
            *(bf16x8*)(&Bs[srow * 64 + p0]) = w0;
            *(bf16x8*)(&Bs[srow * 64 + p1]) = w1;
        }
        __syncthreads();
#pragma unroll
        for (int ks = 0; ks < 2; ks++) {
            bf16x8 a[2], b[2];
#pragma unroll
            for (int i = 0; i < 2; i++) {
                int ma = wr * 32 + i * 16 + fr;
                a[i] = *(const bf16x8*)(&As[ma * 64 + ((ks * 4 + gq) ^ (ma & 7)) * 8]);
                int nb = wc * 32 + i * 16 + fr;
                b[i] = *(const bf16x8*)(&Bs[nb * 64 + ((ks * 4 + gq) ^ (nb & 7)) * 8]);
            }
#pragma unroll
            for (int i = 0; i < 2; i++)
#pragma unroll
                for (int j = 0; j < 2; j++)
                    acc[i][j] = __builtin_amdgcn_mfma_f32_16x16x32_bf16(a[i], b[j], acc[i][j], 0, 0, 0);
        }
        __syncthreads();
    }
    int orow = gq * 4;
#pragma unroll
    for (int i = 0; i < 2; i++)
#pragma unroll
        for (int j = 0; j < 2; j++) {
            int gn = n0 + wc * 32 + j * 16 + fr;
            float bv = bias[gn];
#pragma unroll
            for (int r = 0; r < 4; r++) {
                int gm = m0 + wr * 32 + i * 16 + orow + r;
                if (gm < M) {
                    float v = acc[i][j][r] + bv;
                    if (RELU) v = fmaxf(v, 0.f);
                    stval(C + (size_t)gm * N + gn, v);
                }
            }
        }
}

// ---------------- elementwise add ----------------
__global__ void add2(const float* __restrict__ a, const float* __restrict__ b,
                     float* __restrict__ o, int n) {
    int i = blockIdx.x * blockDim.x + threadIdx.x;
    if (i < n) o[i] = a[i] + b[i];
}

__global__ void fillmark(float* o, int n, float v) {
    int i = blockIdx.x * blockDim.x + threadIdx.x;
    if (i < n) o[i] = v;
}

// ---------------- residual + layernorm ----------------
__global__ void ln_res(const float* a, const float* b,
                       const float* g, const float* be, float* o) {
    int row = blockIdx.x;
    int t = threadIdx.x;
    float x = a[(size_t)row * DD + t] + b[(size_t)row * DD + t];
    __shared__ float red[DD];
    red[t] = x;
    __syncthreads();
    for (int s = 128; s > 0; s >>= 1) {
        if (t < s) red[t] += red[t + s];
        __syncthreads();
    }
    float m = red[0] * (1.f / DD);
    __syncthreads();
    float d0 = x - m;
    red[t] = d0 * d0;
    __syncthreads();
    for (int s = 128; s > 0; s >>= 1) {
        if (t < s) red[t] += red[t + s];
        __syncthreads();
    }
    float v = red[0] * (1.f / DD);
    o[(size_t)row * DD + t] = d0 * rsqrtf(v + 1e-5f) * g[t] + be[t];
}

// ---------------- MFMA flash self-attention ----------------
// one block (4 waves) per (b, h, 64-row Q tile); each wave owns 16 Q rows.
#define QT 64
#define KT 64
#define NT ((NQQ + KT - 1) / KT)   // 15

__global__ __launch_bounds__(256) void sa_attn_mfma(
    const __bf16* __restrict__ Q, const __bf16* __restrict__ K,
    const __bf16* __restrict__ V, float* __restrict__ O) {
    int blk = blockIdx.x;
    int tq = blk % NT;
    int bh = blk / NT;
    int h = bh % NH;
    int b = bh / NH;
    int tid = threadIdx.x;
    int lane = tid & 63;
    int wave = tid >> 6;
    int fr = lane & 15, gq = lane >> 4;
    int q0 = tq * QT;

    __shared__ __attribute__((aligned(16))) __bf16 Ks[KT][56];     // row-major K tile
    __shared__ __attribute__((aligned(16))) __bf16 Vt[HDIM][72];   // transposed V tile
    __shared__ __attribute__((aligned(16))) __bf16 Ps[4][16][72];  // per-wave P

    // Q fragment (constant over KV loop): row = q0+wave*16+fr, k = gq*8..+8
    int qrow = q0 + wave * 16 + fr;
    bf16x8 aq = {};
    if (qrow < NQQ)
        aq = *(const bf16x8*)(Q + ((size_t)(b * NQQ + qrow)) * DD + h * HDIM + gq * 8);

    f32x4 o0 = {}, o1 = {};
    float m_r[4] = {-1e30f, -1e30f, -1e30f, -1e30f};
    float l_r[4] = {0.f, 0.f, 0.f, 0.f};
    const float scale = 0.17677669529663687f;

    for (int kt = 0; kt < NT; kt++) {
        int kv0 = kt * KT;
        // ---- stage K (row-major) and V (transposed) ----
        {
            int r = tid >> 2;
            int c8 = (tid & 3) * 8;
            int kvr = kv0 + r;
            bf16x8 kv_ = {}, vv_ = {};
            if (kvr < NQQ) {
                kv_ = *(const bf16x8*)(K + ((size_t)(b * NQQ + kvr)) * DD + h * HDIM + c8);
                vv_ = *(const bf16x8*)(V + ((size_t)(b * NQQ + kvr)) * DD + h * HDIM + c8);
            }
            *(bf16x8*)(&Ks[r][c8]) = kv_;
#pragma unroll
            for (int j = 0; j < 8; j++) Vt[c8 + j][r] = vv_[j];
        }
        __syncthreads();

        // ---- S = Q K^T (4 fragments of 16 kv cols) ----
        f32x4 s[4];
#pragma unroll
        for (int f = 0; f < 4; f++) {
            bf16x8 bk = *(const bf16x8*)(&Ks[f * 16 + fr][gq * 8]);
            f32x4 z = {};
            s[f] = __builtin_amdgcn_mfma_f32_16x16x32_bf16(aq, bk, z, 0, 0, 0);
        }
        // scale + mask
#pragma unroll
        for (int f = 0; f < 4; f++) {
            bool valid = (kv0 + f * 16 + fr) < NQQ;
#pragma unroll
            for (int r = 0; r < 4; r++)
                s[f][r] = valid ? s[f][r] * scale : -1e30f;
        }
        // row max (reduce over 4 frags + 16-lane group)
        float sc_[4];
#pragma unroll
        for (int r = 0; r < 4; r++) {
            float v = fmaxf(fmaxf(s[0][r], s[1][r]), fmaxf(s[2][r], s[3][r]));
            v = fmaxf(v, __shfl_xor(v, 1));
            v = fmaxf(v, __shfl_xor(v, 2));
            v = fmaxf(v, __shfl_xor(v, 4));
            v = fmaxf(v, __shfl_xor(v, 8));
            float mn = fmaxf(m_r[r], v);
            sc_[r] = expf(m_r[r] - mn);
            m_r[r] = mn;
        }
        // P = exp(s - m), row sum
        float rs[4] = {0.f, 0.f, 0.f, 0.f};
#pragma unroll
        for (int f = 0; f < 4; f++)
#pragma unroll
            for (int r = 0; r < 4; r++) {
                float e = expf(s[f][r] - m_r[r]);
                s[f][r] = e;
                rs[r] += e;
            }
#pragma unroll
        for (int r = 0; r < 4; r++) {
            float v = rs[r];
            v += __shfl_xor(v, 1);
            v += __shfl_xor(v, 2);
            v += __shfl_xor(v, 4);
            v += __shfl_xor(v, 8);
            l_r[r] = l_r[r] * sc_[r] + v;
            o0[r] *= sc_[r];
            o1[r] *= sc_[r];
        }
        // P -> LDS (C-layout write), per-wave
#pragma unroll
        for (int f = 0; f < 4; f++)
#pragma unroll
            for (int r = 0; r < 4; r++)
                Ps[wave][gq * 4 + r][f * 16 + fr] = (__bf16)s[f][r];
        // ---- O += P V ----
#pragma unroll
        for (int c = 0; c < 2; c++) {
            bf16x8 ap = *(const bf16x8*)(&Ps[wave][fr][c * 32 + gq * 8]);
            bf16x8 bv0 = *(const bf16x8*)(&Vt[fr][c * 32 + gq * 8]);
            bf16x8 bv1 = *(const bf16x8*)(&Vt[16 + fr][c * 32 + gq * 8]);
            o0 = __builtin_amdgcn_mfma_f32_16x16x32_bf16(ap, bv0, o0, 0, 0, 0);
            o1 = __builtin_amdgcn_mfma_f32_16x16x32_bf16(ap, bv1, o1, 0, 0, 0);
        }
        __syncthreads();
    }
    // epilogue
#pragma unroll
    for (int r = 0; r < 4; r++) {
        int qr = q0 + wave * 16 + gq * 4 + r;
        if (qr < NQQ) {
            float inv = 1.f / l_r[r];
            O[((size_t)(b * NQQ + qr)) * DD + h * HDIM + fr] = o0[r] * inv;
            O[((size_t)(b * NQQ + qr)) * DD + h * HDIM + 16 + fr] = o1[r] * inv;
        }
    }
}

// ---------------- msdeform sampling (bf16 value/off/aw) ----------------
__device__ inline float tapb(const __bf16* __restrict__ vbase, int xi, int yi, int Wl, int Hl) {
    if (xi < 0 || xi >= Wl || yi < 0 || yi >= Hl) return 0.f;
    return (float)vbase[(size_t)(yi * Wl + xi) * DD];
}

__global__ void msdeform(const __bf16* __restrict__ val, const __bf16* __restrict__ off,
                         const __bf16* __restrict__ awl, const float* __restrict__ ref,
                         float* __restrict__ out) {
    int blk = blockIdx.x;
    int b = blk / NQQ;
    int qi = blk % NQQ;
    int t = threadIdx.x;
    int h = t >> 5, d = t & 31;
    const int Hs[4] = {128, 64, 32, 16};
    const int Wsz[4] = {128, 64, 32, 16};
    const int stt[4] = {0, 16384, 20480, 21504};
    const __bf16* offrow = off + (size_t)blk * 256 + h * 32;
    const __bf16* awrow = awl + (size_t)blk * 128 + h * 16;
    float mx = -1e30f;
#pragma unroll
    for (int i = 0; i < 16; i++) mx = fmaxf(mx, (float)awrow[i]);
    float ssum = 0.f;
    float aw[16];
#pragma unroll
    for (int i = 0; i < 16; i++) {
        aw[i] = expf((float)awrow[i] - mx);
        ssum += aw[i];
    }
    float inv = 1.f / ssum;
    float acc = 0.f;
#pragma unroll
    for (int l = 0; l < LV; l++) {
        const float* rp = ref + ((size_t)(b * NQQ + qi) * LV + l) * 4;
        float cx = rp[0], cy = rp[1], rw = rp[2], rh = rp[3];
        int Wl = Wsz[l], Hl = Hs[l];
        const __bf16* vbase = val + ((size_t)b * SS + stt[l]) * DD + h * HDIM + d;
#pragma unroll
        for (int p = 0; p < NP; p++) {
            float ox = (float)offrow[l * 8 + p * 2 + 0], oy = (float)offrow[l * 8 + p * 2 + 1];
            float lx = cx + ox * (1.0f / NP) * rw * 0.5f;
            float ly = cy + oy * (1.0f / NP) * rh * 0.5f;
            float x = lx * Wl - 0.5f, y = ly * Hl - 0.5f;
            float x0f = floorf(x), y0f = floorf(y);
            float dx = x - x0f, dy = y - y0f;
            int x0 = (int)x0f, y0 = (int)y0f;
            float w00 = (1 - dx) * (1 - dy), w10 = dx * (1 - dy);
            float w01 = (1 - dx) * dy, w11 = dx * dy;
            float sv = w00 * tapb(vbase, x0, y0, Wl, Hl) + w10 * tapb(vbase, x0 + 1, y0, Wl, Hl) +
                       w01 * tapb(vbase, x0, y0 + 1, Wl, Hl) + w11 * tapb(vbase, x0 + 1, y0 + 1, Wl, Hl);
            acc += aw[l * 4 + p] * inv * sv;
        }
    }
    out[(size_t)blk * DD + h * HDIM + d] = acc;
}

// ---------------- launch ----------------
extern "C" void kernel_launch(void* const* d_in, const int* in_sizes, int n_in,
                              void* d_out, int out_size, void* d_ws, size_t ws_size,
                              hipStream_t stream) {
    const float* query      = (const float*)d_in[0];
    const float* query_pos  = (const float*)d_in[1];
    const float* refpts     = (const float*)d_in[2];
    const float* input_flat = (const float*)d_in[3];
    const float* sa_in_w    = (const float*)d_in[6];
    const float* sa_in_b    = (const float*)d_in[7];
    const float* sa_out_w   = (const float*)d_in[8];
    const float* sa_out_b   = (const float*)d_in[9];
    const float* norm1_g    = (const float*)d_in[10];
    const float* norm1_b    = (const float*)d_in[11];
    const float* value_w    = (const float*)d_in[12];
    const float* value_b    = (const float*)d_in[13];
    const float* off_w      = (const float*)d_in[14];
    const float* off_b      = (const float*)d_in[15];
    const float* aw_w       = (const float*)d_in[16];
    const float* aw_b       = (const float*)d_in[17];
    const float* ca_out_w   = (const float*)d_in[18];
    const float* ca_out_b   = (const float*)d_in[19];
    const float* norm2_g    = (const float*)d_in[20];
    const float* norm2_b    = (const float*)d_in[21];
    const float* lin1_w     = (const float*)d_in[22];
    const float* lin1_b     = (const float*)d_in[23];
    const float* lin2_w     = (const float*)d_in[24];
    const float* lin2_b     = (const float*)d_in[25];
    const float* norm3_g    = (const float*)d_in[26];
    const float* norm3_b    = (const float*)d_in[27];
    float* out = (float*)d_out;

    const int M = BB * NQQ;              // 3600
    const int NE = M * DD;               // 921600
    const size_t slotBytes = (size_t)NE * 4;
    const size_t wElems = 6 * 65536 + 32768 + 65536 + 2 * 524288;
    const size_t wBytes = wElems * 2;
    const size_t bigBytes = (size_t)BB * SS * DD * 2;
    const size_t needBytes = 3 * slotBytes + wBytes + bigBytes;
    if (ws_size < needBytes) {
        float mark = 1000.0f + (float)(ws_size >> 20);
        fillmark<<<(out_size + 255) / 256, 256, 0, stream>>>(out, out_size, mark);
        return;
    }

    char* wsb = (char*)d_ws;
    float* s0 = (float*)(wsb);
    float* s1 = (float*)(wsb + slotBytes);
    float* s2 = (float*)(wsb + 2 * slotBytes);
    __bf16* wb = (__bf16*)(wsb + 3 * slotBytes);
    __bf16* vbig = (__bf16*)(wsb + 3 * slotBytes + wBytes);

    __bf16* wt_q   = wb;
    __bf16* wt_k   = wb + 65536;
    __bf16* wt_v   = wb + 131072;
    __bf16* wt_sa  = wb + 196608;
    __bf16* wt_val = wb + 262144;
    __bf16* wt_off = wb + 327680;
    __bf16* wt_aw  = wb + 393216;
    __bf16* wt_ca  = wb + 425984;
    __bf16* wt_l1  = wb + 491520;
    __bf16* wt_l2  = wb + 1015808;

    dim3 tb(32, 8);
    transp_cvt<<<dim3(8, 8),  tb, 0, stream>>>(sa_in_w,          wt_q,  DD, DD);
    transp_cvt<<<dim3(8, 8),  tb, 0, stream>>>(sa_in_w + 65536,  wt_k,  DD, DD);
    transp_cvt<<<dim3(8, 8),  tb, 0, stream>>>(sa_in_w + 131072, wt_v,  DD, DD);
    transp_cvt<<<dim3(8, 8),  tb, 0, stream>>>(sa_out_w,         wt_sa, DD, DD);
    transp_cvt<<<dim3(8, 8),  tb, 0, stream>>>(value_w,          wt_val, DD, DD);
    transp_cvt<<<dim3(8, 8),  tb, 0, stream>>>(off_w,            wt_off, DD, DD);
    transp_cvt<<<dim3(4, 8),  tb, 0, stream>>>(aw_w,             wt_aw, DD, 128);
    transp_cvt<<<dim3(8, 8),  tb, 0, stream>>>(ca_out_w,         wt_ca, DD, DD);
    transp_cvt<<<dim3(64, 8), tb, 0, stream>>>(lin1_w,           wt_l1, DD, DFF);
    transp_cvt<<<dim3(8, 64), tb, 0, stream>>>(lin2_w,           wt_l2, DFF, DD);

    __bf16* Qp = (__bf16*)s1;
    __bf16* Kp = (__bf16*)s1 + NE;
    __bf16* Vp = (__bf16*)s2;
    __bf16* offb = (__bf16*)s1;
    __bf16* awb = (__bf16*)s1 + NE;

    const int mt = (M + BM - 1) / BM;    // 57
    const int mtv = (BB * SS) / BM;      // 1360

    add2<<<(NE + 255) / 256, 256, 0, stream>>>(query, query_pos, s0, NE);
    mfma_gemm<float, __bf16, 0><<<dim3(4, mt), 256, 0, stream>>>(s0, wt_q, sa_in_b, Qp, M, DD, DD);
    mfma_gemm<float, __bf16, 0><<<dim3(4, mt), 256, 0, stream>>>(s0, wt_k, sa_in_b + 256, Kp, M, DD, DD);
    mfma_gemm<float, __bf16, 0><<<dim3(4, mt), 256, 0, stream>>>(query, wt_v, sa_in_b + 512, Vp, M, DD, DD);
    sa_attn_mfma<<<BB * NH * NT, 256, 0, stream>>>(Qp, Kp, Vp, s0);
    mfma_gemm<float, float, 0><<<dim3(4, mt), 256, 0, stream>>>(s0, wt_sa, sa_out_b, s1, M, DD, DD);
    ln_res<<<M, DD, 0, stream>>>(query, s1, norm1_g, norm1_b, s2);
    add2<<<(NE + 255) / 256, 256, 0, stream>>>(s2, query_pos, s0, NE);
    mfma_gemm<float, __bf16, 0><<<dim3(4, mtv), 256, 0, stream>>>(input_flat, wt_val, value_b, vbig, BB * SS, DD, DD);
    mfma_gemm<float, __bf16, 0><<<dim3(4, mt), 256, 0, stream>>>(s0, wt_off, off_b, offb, M, DD, DD);
    mfma_gemm<float, __bf16, 0><<<dim3(2, mt), 256, 0, stream>>>(s0, wt_aw, aw_b, awb, M, 128, DD);
    msdeform<<<BB * NQQ, 256, 0, stream>>>(vbig, offb, awb, refpts, s0);
    mfma_gemm<float, float, 0><<<dim3(4, mt), 256, 0, stream>>>(s0, wt_ca, ca_out_b, s1, M, DD, DD);
    ln_res<<<M, DD, 0, stream>>>(s2, s1, norm2_g, norm2_b, s1);
    mfma_gemm<float, __bf16, 1><<<dim3(32, mt), 256, 0, stream>>>(s1, wt_l1, lin1_b, vbig, M, DFF, DD);
    mfma_gemm<__bf16, float, 0><<<dim3(4, mt), 256, 0, stream>>>(vbig, wt_l2, lin2_b, s0, M, DD, DFF);
    ln_res<<<M, DD, 0, stream>>>(s1, s0, norm3_g, norm3_b, out);
}

// Round 6
// 301.631 us; speedup vs baseline: 7.2305x; 1.1972x over previous
//
#include <hip/hip_runtime.h>
#include <hip/hip_bf16.h>

#define DD   256
#define NH   8
#define HDIM 32
#define LV   4
#define NP   4
#define DFF  2048
#define BB   4
#define NQQ  900
#define SS   21760

typedef __bf16 bf16x8 __attribute__((ext_vector_type(8)));
typedef __bf16 bf16x2 __attribute__((ext_vector_type(2)));
typedef float  f32x4  __attribute__((ext_vector_type(4)));

__device__ inline void stval(float* p, float v) { *p = v; }
__device__ inline void stval(__bf16* p, float v) { *p = (__bf16)v; }

// ============ all weight transposes in ONE launch ============================
struct TPtrs {
    const float* s[10];
    __bf16* d[10];
};

__global__ void transp_all(TPtrs P) {
    // jobs: q k v sa val off aw ca l1 l2
    const int Ks[10] = {256, 256, 256, 256, 256, 256, 256, 256, 256, 2048};
    const int Ns[10] = {256, 256, 256, 256, 256, 256, 128, 256, 2048, 256};
    const int tiles[10] = {64, 64, 64, 64, 64, 64, 32, 64, 512, 512};
    int t = blockIdx.x;
    int j = 0, base = 0;
    while (t >= base + tiles[j]) { base += tiles[j]; j++; }
    int lt = t - base;
    int K = Ks[j], N = Ns[j];
    int tn = N >> 5;
    int nb = (lt % tn) * 32, kb = (lt / tn) * 32;
    const float* W = P.s[j];
    __bf16* Wt = P.d[j];
    __shared__ float tbuf[32][33];
    for (int i = threadIdx.y; i < 32; i += 8)
        tbuf[i][threadIdx.x] = W[(size_t)(kb + i) * N + nb + threadIdx.x];
    __syncthreads();
    for (int i = threadIdx.y; i < 32; i += 8)
        Wt[(size_t)(nb + i) * K + kb + threadIdx.x] = (__bf16)tbuf[threadIdx.x][i];
}

// ============ MFMA GEMM: C = (A[+A2]) @ Wt^T + bias(split) ==================
#define BM 64
#define BN 64
#define BKK 64

template <typename AT, typename OT, int RELU>
__global__ __launch_bounds__(256) void mfma_gemm(
    const AT* __restrict__ A, const float* __restrict__ A2,
    const __bf16* __restrict__ Wt,
    const float* __restrict__ bias, const float* __restrict__ bias2, int nsplit,
    OT* __restrict__ C, int M, int N, int K) {
    int tid = threadIdx.x;
    int lane = tid & 63;
    int wave = tid >> 6;
    int wr = wave >> 1, wc = wave & 1;
    int m0 = blockIdx.y * BM;
    int n0 = blockIdx.x * BN;

    __shared__ __attribute__((aligned(16))) __bf16 As[BM * BKK];
    __shared__ __attribute__((aligned(16))) __bf16 Bs[BN * BKK];

    f32x4 acc[2][2] = {};

    int srow = tid >> 2;
    int sq = tid & 3;
    int u0 = sq << 1;
    int p0 = (u0 ^ (srow & 7)) * 8;
    int p1 = ((u0 + 1) ^ (srow & 7)) * 8;
    int fr = lane & 15, gq = lane >> 4;

    for (int k0 = 0; k0 < K; k0 += BKK) {
        {
            int gm = m0 + srow;
            bf16x8 v0 = {}, v1 = {};
            if (gm < M) {
                if constexpr (sizeof(AT) == 4) {
                    const float* ap = (const float*)A + (size_t)gm * K + k0 + sq * 16;
                    f32x4 f0 = *(const f32x4*)(ap + 0);
                    f32x4 f1 = *(const f32x4*)(ap + 4);
                    f32x4 f2 = *(const f32x4*)(ap + 8);
                    f32x4 f3 = *(const f32x4*)(ap + 12);
                    if (A2) {
                        const float* ap2 = A2 + (size_t)gm * K + k0 + sq * 16;
                        f0 += *(const f32x4*)(ap2 + 0);
                        f1 += *(const f32x4*)(ap2 + 4);
                        f2 += *(const f32x4*)(ap2 + 8);
                        f3 += *(const f32x4*)(ap2 + 12);
                    }
#pragma unroll
                    for (int e = 0; e < 4; e++) {
                        v0[e] = (__bf16)f0[e]; v0[e + 4] = (__bf16)f1[e];
                        v1[e] = (__bf16)f2[e]; v1[e + 4] = (__bf16)f3[e];
                    }
                } else {
                    const __bf16* ap = (const __bf16*)A + (size_t)gm * K + k0 + sq * 16;
                    v0 = *(const bf16x8*)(ap);
                    v1 = *(const bf16x8*)(ap + 8);
                }
            }
            *(bf16x8*)(&As[srow * 64 + p0]) = v0;
            *(bf16x8*)(&As[srow * 64 + p1]) = v1;
        }
        {
            int gn = n0 + srow;
            const __bf16* bp = Wt + (size_t)gn * K + k0 + sq * 16;
            bf16x8 w0 = *(const bf16x8*)(bp);
            bf16x8 w1 = *(const bf16x8*)(bp + 8);
            *(bf16x8*)(&Bs[srow * 64 + p0]) = w0;
            *(bf16x8*)(&Bs[srow * 64 + p1]) = w1;
        }
        __syncthreads();
#pragma unroll
        for (int ks = 0; ks < 2; ks++) {
            bf16x8 a[2], b[2];
#pragma unroll
            for (int i = 0; i < 2; i++) {
                int ma = wr * 32 + i * 16 + fr;
                a[i] = *(const bf16x8*)(&As[ma * 64 + ((ks * 4 + gq) ^ (ma & 7)) * 8]);
                int nb = wc * 32 + i * 16 + fr;
                b[i] = *(const bf16x8*)(&Bs[nb * 64 + ((ks * 4 + gq) ^ (nb & 7)) * 8]);
            }
#pragma unroll
            for (int i = 0; i < 2; i++)
#pragma unroll
                for (int j = 0; j < 2; j++)
                    acc[i][j] = __builtin_amdgcn_mfma_f32_16x16x32_bf16(a[i], b[j], acc[i][j], 0, 0, 0);
        }
        __syncthreads();
    }
    int orow = gq * 4;
#pragma unroll
    for (int i = 0; i < 2; i++)
#pragma unroll
        for (int j = 0; j < 2; j++) {
            int gn = n0 + wc * 32 + j * 16 + fr;
            float bv = (gn < nsplit) ? bias[gn] : bias2[gn - nsplit];
#pragma unroll
            for (int r = 0; r < 4; r++) {
                int gm = m0 + wr * 32 + i * 16 + orow + r;
                if (gm < M) {
                    float v = acc[i][j][r] + bv;
                    if (RELU) v = fmaxf(v, 0.f);
                    stval(C + (size_t)gm * N + gn, v);
                }
            }
        }
}

__global__ void fillmark(float* o, int n, float v) {
    int i = blockIdx.x * blockDim.x + threadIdx.x;
    if (i < n) o[i] = v;
}

// ---------------- residual + layernorm ----------------
__global__ void ln_res(const float* a, const float* b,
                       const float* g, const float* be, float* o) {
    int row = blockIdx.x;
    int t = threadIdx.x;
    float x = a[(size_t)row * DD + t] + b[(size_t)row * DD + t];
    __shared__ float red[DD];
    red[t] = x;
    __syncthreads();
    for (int s = 128; s > 0; s >>= 1) {
        if (t < s) red[t] += red[t + s];
        __syncthreads();
    }
    float m = red[0] * (1.f / DD);
    __syncthreads();
    float d0 = x - m;
    red[t] = d0 * d0;
    __syncthreads();
    for (int s = 128; s > 0; s >>= 1) {
        if (t < s) red[t] += red[t + s];
        __syncthreads();
    }
    float v = red[0] * (1.f / DD);
    o[(size_t)row * DD + t] = d0 * rsqrtf(v + 1e-5f) * g[t] + be[t];
}

// ---------------- MFMA flash self-attention (QK packed, stride 512) ---------
#define QT 64
#define KT 64
#define NT ((NQQ + KT - 1) / KT)   // 15
#define QKLD 512

__global__ __launch_bounds__(256) void sa_attn_mfma(
    const __bf16* __restrict__ QK, const __bf16* __restrict__ V,
    float* __restrict__ O) {
    int blk = blockIdx.x;
    int tq = blk % NT;
    int bh = blk / NT;
    int h = bh % NH;
    int b = bh / NH;
    int tid = threadIdx.x;
    int lane = tid & 63;
    int wave = tid >> 6;
    int fr = lane & 15, gq = lane >> 4;
    int q0 = tq * QT;

    __shared__ __attribute__((aligned(16))) __bf16 Ks[KT][56];
    __shared__ __attribute__((aligned(16))) __bf16 Vt[HDIM][72];
    __shared__ __attribute__((aligned(16))) __bf16 Ps[4][16][72];

    int qrow = q0 + wave * 16 + fr;
    bf16x8 aq = {};
    if (qrow < NQQ)
        aq = *(const bf16x8*)(QK + ((size_t)(b * NQQ + qrow)) * QKLD + h * HDIM + gq * 8);

    f32x4 o0 = {}, o1 = {};
    float m_r[4] = {-1e30f, -1e30f, -1e30f, -1e30f};
    float l_r[4] = {0.f, 0.f, 0.f, 0.f};
    const float scale = 0.17677669529663687f;

    for (int kt = 0; kt < NT; kt++) {
        int kv0 = kt * KT;
        {
            int r = tid >> 2;
            int c8 = (tid & 3) * 8;
            int kvr = kv0 + r;
            bf16x8 kv_ = {}, vv_ = {};
            if (kvr < NQQ) {
                kv_ = *(const bf16x8*)(QK + ((size_t)(b * NQQ + kvr)) * QKLD + 256 + h * HDIM + c8);
                vv_ = *(const bf16x8*)(V + ((size_t)(b * NQQ + kvr)) * DD + h * HDIM + c8);
            }
            *(bf16x8*)(&Ks[r][c8]) = kv_;
#pragma unroll
            for (int j = 0; j < 8; j++) Vt[c8 + j][r] = vv_[j];
        }
        __syncthreads();

        f32x4 s[4];
#pragma unroll
        for (int f = 0; f < 4; f++) {
            bf16x8 bk = *(const bf16x8*)(&Ks[f * 16 + fr][gq * 8]);
            f32x4 z = {};
            s[f] = __builtin_amdgcn_mfma_f32_16x16x32_bf16(aq, bk, z, 0, 0, 0);
        }
#pragma unroll
        for (int f = 0; f < 4; f++) {
            bool valid = (kv0 + f * 16 + fr) < NQQ;
#pragma unroll
            for (int r = 0; r < 4; r++)
                s[f][r] = valid ? s[f][r] * scale : -1e30f;
        }
        float sc_[4];
#pragma unroll
        for (int r = 0; r < 4; r++) {
            float v = fmaxf(fmaxf(s[0][r], s[1][r]), fmaxf(s[2][r], s[3][r]));
            v = fmaxf(v, __shfl_xor(v, 1));
            v = fmaxf(v, __shfl_xor(v, 2));
            v = fmaxf(v, __shfl_xor(v, 4));
            v = fmaxf(v, __shfl_xor(v, 8));
            float mn = fmaxf(m_r[r], v);
            sc_[r] = expf(m_r[r] - mn);
            m_r[r] = mn;
        }
        float rs[4] = {0.f, 0.f, 0.f, 0.f};
#pragma unroll
        for (int f = 0; f < 4; f++)
#pragma unroll
            for (int r = 0; r < 4; r++) {
                float e = expf(s[f][r] - m_r[r]);
                s[f][r] = e;
                rs[r] += e;
            }
#pragma unroll
        for (int r = 0; r < 4; r++) {
            float v = rs[r];
            v += __shfl_xor(v, 1);
            v += __shfl_xor(v, 2);
            v += __shfl_xor(v, 4);
            v += __shfl_xor(v, 8);
            l_r[r] = l_r[r] * sc_[r] + v;
            o0[r] *= sc_[r];
            o1[r] *= sc_[r];
        }
#pragma unroll
        for (int f = 0; f < 4; f++)
#pragma unroll
            for (int r = 0; r < 4; r++)
                Ps[wave][gq * 4 + r][f * 16 + fr] = (__bf16)s[f][r];
#pragma unroll
        for (int c = 0; c < 2; c++) {
            bf16x8 ap = *(const bf16x8*)(&Ps[wave][fr][c * 32 + gq * 8]);
            bf16x8 bv0 = *(const bf16x8*)(&Vt[fr][c * 32 + gq * 8]);
            bf16x8 bv1 = *(const bf16x8*)(&Vt[16 + fr][c * 32 + gq * 8]);
            o0 = __builtin_amdgcn_mfma_f32_16x16x32_bf16(ap, bv0, o0, 0, 0, 0);
            o1 = __builtin_amdgcn_mfma_f32_16x16x32_bf16(ap, bv1, o1, 0, 0, 0);
        }
        __syncthreads();
    }
#pragma unroll
    for (int r = 0; r < 4; r++) {
        int qr = q0 + wave * 16 + gq * 4 + r;
        if (qr < NQQ) {
            float inv = 1.f / l_r[r];
            O[((size_t)(b * NQQ + qr)) * DD + h * HDIM + fr] = o0[r] * inv;
            O[((size_t)(b * NQQ + qr)) * DD + h * HDIM + 16 + fr] = o1[r] * inv;
        }
    }
}

// ---------------- msdeform v2: 2 queries/block, LDS-staged coords ------------
// phase1: tid=(qq,h,lp) computes softmax weight + sample coords -> LDS
// phase2: tid=(qq,h,dpair) gathers bf16x2 taps
#define OAW 384

__global__ __launch_bounds__(256) void msdeform2(
    const __bf16* __restrict__ val, const __bf16* __restrict__ oa,
    const float* __restrict__ ref, float* __restrict__ out) {
    int tid = threadIdx.x;
    int qq = tid >> 7;
    int row = blockIdx.x * 2 + qq;          // flat (b*NQQ+q), pairs never straddle b
    int b_ = row / NQQ;

    __shared__ float sx[256], sy[256], sw[256];

    // ---- phase 1 ----
    {
        int h = (tid >> 4) & 7;
        int lp = tid & 15;
        int l = lp >> 2;
        float logit = (float)oa[(size_t)row * OAW + 256 + h * 16 + lp];
        float ox = (float)oa[(size_t)row * OAW + h * 32 + lp * 2];
        float oy = (float)oa[(size_t)row * OAW + h * 32 + lp * 2 + 1];
        const float* rp = ref + ((size_t)row * LV + l) * 4;
        float cx = rp[0], cy = rp[1], rw = rp[2], rh = rp[3];
        float mv = logit;
        mv = fmaxf(mv, __shfl_xor(mv, 1));
        mv = fmaxf(mv, __shfl_xor(mv, 2));
        mv = fmaxf(mv, __shfl_xor(mv, 4));
        mv = fmaxf(mv, __shfl_xor(mv, 8));
        float e = expf(logit - mv);
        float sum = e;
        sum += __shfl_xor(sum, 1);
        sum += __shfl_xor(sum, 2);
        sum += __shfl_xor(sum, 4);
        sum += __shfl_xor(sum, 8);
        int Wl = 128 >> l, Hl = 128 >> l;
        float lx = cx + ox * (1.0f / NP) * rw * 0.5f;
        float ly = cy + oy * (1.0f / NP) * rh * 0.5f;
        sx[tid] = lx * Wl - 0.5f;
        sy[tid] = ly * Hl - 0.5f;
        sw[tid] = e / sum;
    }
    __syncthreads();

    // ---- phase 2 ----
    int h = (tid >> 4) & 7;
    int dp = tid & 15;
    const __bf16* vb = val + ((size_t)b_ * SS) * DD + h * HDIM + dp * 2;
    float accx = 0.f, accy = 0.f;
    const int stt[4] = {0, 16384, 20480, 21504};
#pragma unroll
    for (int lp = 0; lp < 16; lp++) {
        int l = lp >> 2;
        int Wl = 128 >> l, Hl = 128 >> l;
        int idx = qq * 128 + h * 16 + lp;
        float x = sx[idx], y = sy[idx], w = sw[idx];
        float x0f = floorf(x), y0f = floorf(y);
        float dx = x - x0f, dy = y - y0f;
        int x0 = (int)x0f, y0 = (int)y0f;
        float w00 = (1 - dx) * (1 - dy), w10 = dx * (1 - dy);
        float w01 = (1 - dx) * dy, w11 = dx * dy;
        const __bf16* lb = vb + (size_t)stt[l] * DD;
        float t00x = 0.f, t00y = 0.f, t10x = 0.f, t10y = 0.f;
        float t01x = 0.f, t01y = 0.f, t11x = 0.f, t11y = 0.f;
        bool vx0 = (x0 >= 0) & (x0 < Wl), vx1 = (x0 + 1 >= 0) & (x0 + 1 < Wl);
        bool vy0 = (y0 >= 0) & (y0 < Hl), vy1 = (y0 + 1 >= 0) & (y0 + 1 < Hl);
        if (vx0 & vy0) { bf16x2 t = *(const bf16x2*)(lb + (size_t)(y0 * Wl + x0) * DD); t00x = (float)t[0]; t00y = (float)t[1]; }
        if (vx1 & vy0) { bf16x2 t = *(const bf16x2*)(lb + (size_t)(y0 * Wl + x0 + 1) * DD); t10x = (float)t[0]; t10y = (float)t[1]; }
        if (vx0 & vy1) { bf16x2 t = *(const bf16x2*)(lb + (size_t)((y0 + 1) * Wl + x0) * DD); t01x = (float)t[0]; t01y = (float)t[1]; }
        if (vx1 & vy1) { bf16x2 t = *(const bf16x2*)(lb + (size_t)((y0 + 1) * Wl + x0 + 1) * DD); t11x = (float)t[0]; t11y = (float)t[1]; }
        accx += w * (w00 * t00x + w10 * t10x + w01 * t01x + w11 * t11x);
        accy += w * (w00 * t00y + w10 * t10y + w01 * t01y + w11 * t11y);
    }
    out[(size_t)row * DD + h * HDIM + dp * 2] = accx;
    out[(size_t)row * DD + h * HDIM + dp * 2 + 1] = accy;
}

// ---------------- launch ----------------
extern "C" void kernel_launch(void* const* d_in, const int* in_sizes, int n_in,
                              void* d_out, int out_size, void* d_ws, size_t ws_size,
                              hipStream_t stream) {
    const float* query      = (const float*)d_in[0];
    const float* query_pos  = (const float*)d_in[1];
    const float* refpts     = (const float*)d_in[2];
    const float* input_flat = (const float*)d_in[3];
    const float* sa_in_w    = (const float*)d_in[6];
    const float* sa_in_b    = (const float*)d_in[7];
    const float* sa_out_w   = (const float*)d_in[8];
    const float* sa_out_b   = (const float*)d_in[9];
    const float* norm1_g    = (const float*)d_in[10];
    const float* norm1_b    = (const float*)d_in[11];
    const float* value_w    = (const float*)d_in[12];
    const float* value_b    = (const float*)d_in[13];
    const float* off_w      = (const float*)d_in[14];
    const float* off_b      = (const float*)d_in[15];
    const float* aw_w       = (const float*)d_in[16];
    const float* aw_b       = (const float*)d_in[17];
    const float* ca_out_w   = (const float*)d_in[18];
    const float* ca_out_b   = (const float*)d_in[19];
    const float* norm2_g    = (const float*)d_in[20];
    const float* norm2_b    = (const float*)d_in[21];
    const float* lin1_w     = (const float*)d_in[22];
    const float* lin1_b     = (const float*)d_in[23];
    const float* lin2_w     = (const float*)d_in[24];
    const float* lin2_b     = (const float*)d_in[25];
    const float* norm3_g    = (const float*)d_in[26];
    const float* norm3_b    = (const float*)d_in[27];
    float* out = (float*)d_out;

    const int M = BB * NQQ;              // 3600
    const int NE = M * DD;               // 921600
    const size_t slotBytes = (size_t)NE * 4;
    const size_t wElems = 6 * 65536 + 32768 + 65536 + 2 * 524288;
    const size_t wBytes = wElems * 2;
    const size_t bigBytes = (size_t)BB * SS * DD * 2;
    const size_t needBytes = 3 * slotBytes + wBytes + bigBytes;
    if (ws_size < needBytes) {
        float mark = 1000.0f + (float)(ws_size >> 20);
        fillmark<<<(out_size + 255) / 256, 256, 0, stream>>>(out, out_size, mark);
        return;
    }

    char* wsb = (char*)d_ws;
    float* s0 = (float*)(wsb);
    float* s1 = (float*)(wsb + slotBytes);
    float* s2 = (float*)(wsb + 2 * slotBytes);
    __bf16* wb = (__bf16*)(wsb + 3 * slotBytes);
    __bf16* vbig = (__bf16*)(wsb + 3 * slotBytes + wBytes);

    __bf16* wt_q   = wb;                 // [512][256] combined with wt_k
    __bf16* wt_k   = wb + 65536;
    __bf16* wt_v   = wb + 131072;
    __bf16* wt_sa  = wb + 196608;
    __bf16* wt_val = wb + 262144;
    __bf16* wt_off = wb + 327680;        // [384][256] combined with wt_aw
    __bf16* wt_aw  = wb + 393216;
    __bf16* wt_ca  = wb + 425984;
    __bf16* wt_l1  = wb + 491520;
    __bf16* wt_l2  = wb + 1015808;

    TPtrs tp;
    tp.s[0] = sa_in_w;          tp.d[0] = wt_q;
    tp.s[1] = sa_in_w + 65536;  tp.d[1] = wt_k;
    tp.s[2] = sa_in_w + 131072; tp.d[2] = wt_v;
    tp.s[3] = sa_out_w;         tp.d[3] = wt_sa;
    tp.s[4] = value_w;          tp.d[4] = wt_val;
    tp.s[5] = off_w;            tp.d[5] = wt_off;
    tp.s[6] = aw_w;             tp.d[6] = wt_aw;
    tp.s[7] = ca_out_w;         tp.d[7] = wt_ca;
    tp.s[8] = lin1_w;           tp.d[8] = wt_l1;
    tp.s[9] = lin2_w;           tp.d[9] = wt_l2;
    transp_all<<<1504, dim3(32, 8), 0, stream>>>(tp);

    __bf16* qkbuf = (__bf16*)s1;     // [M][512]
    __bf16* Vp = (__bf16*)s2;        // [M][256]
    __bf16* oabuf = (__bf16*)s1;     // [M][384] (after attn, qk dead)

    const int mt = (M + BM - 1) / BM;    // 57
    const int mtv = (BB * SS) / BM;      // 1360
    const int BIG = 1 << 30;

    // QK projection (fused +query_pos), N=512 -> s1
    mfma_gemm<float, __bf16, 0><<<dim3(8, mt), 256, 0, stream>>>(
        query, query_pos, wt_q, sa_in_b, sa_in_b, BIG, qkbuf, M, 512, DD);
    // V projection -> s2
    mfma_gemm<float, __bf16, 0><<<dim3(4, mt), 256, 0, stream>>>(
        query, nullptr, wt_v, sa_in_b + 512, sa_in_b, BIG, Vp, M, DD, DD);
    // attention -> s0
    sa_attn_mfma<<<BB * NH * NT, 256, 0, stream>>>(qkbuf, Vp, s0);
    // sa projection -> s1 (f32)
    mfma_gemm<float, float, 0><<<dim3(4, mt), 256, 0, stream>>>(
        s0, nullptr, wt_sa, sa_out_b, sa_out_b, BIG, s1, M, DD, DD);
    // x1 = LN(query + saproj) -> s2
    ln_res<<<M, DD, 0, stream>>>(query, s1, norm1_g, norm1_b, s2);
    // value projection -> vbig (bf16)
    mfma_gemm<float, __bf16, 0><<<dim3(4, mtv), 256, 0, stream>>>(
        input_flat, nullptr, wt_val, value_b, value_b, BIG, vbig, BB * SS, DD, DD);
    // off+aw projection (fused +query_pos), N=384 -> s1
    mfma_gemm<float, __bf16, 0><<<dim3(6, mt), 256, 0, stream>>>(
        s2, query_pos, wt_off, off_b, aw_b, 256, oabuf, M, OAW, DD);
    // deformable sampling -> s0
    msdeform2<<<M / 2, 256, 0, stream>>>(vbig, oabuf, refpts, s0);
    // ca projection -> s1 (f32)
    mfma_gemm<float, float, 0><<<dim3(4, mt), 256, 0, stream>>>(
        s0, nullptr, wt_ca, ca_out_b, ca_out_b, BIG, s1, M, DD, DD);
    // x2 = LN(x1 + ca) -> s1
    ln_res<<<M, DD, 0, stream>>>(s2, s1, norm2_g, norm2_b, s1);
    // ffn1 -> vbig (bf16, relu)
    mfma_gemm<float, __bf16, 1><<<dim3(32, mt), 256, 0, stream>>>(
        s1, nullptr, wt_l1, lin1_b, lin1_b, BIG, vbig, M, DFF, DD);
    // ffn2 -> s0
    mfma_gemm<__bf16, float, 0><<<dim3(4, mt), 256, 0, stream>>>(
        vbig, nullptr, wt_l2, lin2_b, lin2_b, BIG, s0, M, DD, DFF);
    // out = LN(x2 + ffn2)
    ln_res<<<M, DD, 0, stream>>>(s1, s0, norm3_g, norm3_b, out);
}

// Round 7
// 244.419 us; speedup vs baseline: 8.9229x; 1.2341x over previous
//
#include <hip/hip_runtime.h>
#include <hip/hip_bf16.h>

#define DD   256
#define NH   8
#define HDIM 32
#define LV   4
#define NP   4
#define DFF  2048
#define BB   4
#define NQQ  900
#define SS   21760

typedef __bf16 bf16x8 __attribute__((ext_vector_type(8)));
typedef __bf16 bf16x2 __attribute__((ext_vector_type(2)));
typedef float  f32x4  __attribute__((ext_vector_type(4)));

__device__ inline void stval(float* p, float v) { *p = v; }
__device__ inline void stval(__bf16* p, float v) { *p = (__bf16)v; }

// ============ all weight transposes in ONE launch ============================
struct TPtrs {
    const float* s[10];
    __bf16* d[10];
};

__global__ void transp_all(TPtrs P) {
    // jobs: q k v sa val off aw ca l1 l2
    const int Ks[10] = {256, 256, 256, 256, 256, 256, 256, 256, 256, 2048};
    const int Ns[10] = {256, 256, 256, 256, 256, 256, 128, 256, 2048, 256};
    const int tiles[10] = {64, 64, 64, 64, 64, 64, 32, 64, 512, 512};
    int t = blockIdx.x;
    int j = 0, base = 0;
    while (t >= base + tiles[j]) { base += tiles[j]; j++; }
    int lt = t - base;
    int K = Ks[j], N = Ns[j];
    int tn = N >> 5;
    int nb = (lt % tn) * 32, kb = (lt / tn) * 32;
    const float* W = P.s[j];
    __bf16* Wt = P.d[j];
    __shared__ float tbuf[32][33];
    for (int i = threadIdx.y; i < 32; i += 8)
        tbuf[i][threadIdx.x] = W[(size_t)(kb + i) * N + nb + threadIdx.x];
    __syncthreads();
    for (int i = threadIdx.y; i < 32; i += 8)
        Wt[(size_t)(nb + i) * K + kb + threadIdx.x] = (__bf16)tbuf[threadIdx.x][i];
}

// ============ MFMA GEMM: C = (A[+A2]) @ Wt^T + bias(split) ==================
#define BM 64
#define BN 64
#define BKK 64

template <typename AT, typename OT, int RELU>
__global__ __launch_bounds__(256) void mfma_gemm(
    const AT* __restrict__ A, const float* __restrict__ A2,
    const __bf16* __restrict__ Wt,
    const float* __restrict__ bias, const float* __restrict__ bias2, int nsplit,
    OT* __restrict__ C, int M, int N, int K) {
    int tid = threadIdx.x;
    int lane = tid & 63;
    int wave = tid >> 6;
    int wr = wave >> 1, wc = wave & 1;
    int m0 = blockIdx.y * BM;
    int n0 = blockIdx.x * BN;

    __shared__ __attribute__((aligned(16))) __bf16 As[BM * BKK];
    __shared__ __attribute__((aligned(16))) __bf16 Bs[BN * BKK];

    f32x4 acc[2][2] = {};

    int srow = tid >> 2;
    int sq = tid & 3;
    int u0 = sq << 1;
    int p0 = (u0 ^ (srow & 7)) * 8;
    int p1 = ((u0 + 1) ^ (srow & 7)) * 8;
    int fr = lane & 15, gq = lane >> 4;

    for (int k0 = 0; k0 < K; k0 += BKK) {
        {
            int gm = m0 + srow;
            bf16x8 v0 = {}, v1 = {};
            if (gm < M) {
                if constexpr (sizeof(AT) == 4) {
                    const float* ap = (const float*)A + (size_t)gm * K + k0 + sq * 16;
                    f32x4 f0 = *(const f32x4*)(ap + 0);
                    f32x4 f1 = *(const f32x4*)(ap + 4);
                    f32x4 f2 = *(const f32x4*)(ap + 8);
                    f32x4 f3 = *(const f32x4*)(ap + 12);
                    if (A2) {
                        const float* ap2 = A2 + (size_t)gm * K + k0 + sq * 16;
                        f0 += *(const f32x4*)(ap2 + 0);
                        f1 += *(const f32x4*)(ap2 + 4);
                        f2 += *(const f32x4*)(ap2 + 8);
                        f3 += *(const f32x4*)(ap2 + 12);
                    }
#pragma unroll
                    for (int e = 0; e < 4; e++) {
                        v0[e] = (__bf16)f0[e]; v0[e + 4] = (__bf16)f1[e];
                        v1[e] = (__bf16)f2[e]; v1[e + 4] = (__bf16)f3[e];
                    }
                } else {
                    const __bf16* ap = (const __bf16*)A + (size_t)gm * K + k0 + sq * 16;
                    v0 = *(const bf16x8*)(ap);
                    v1 = *(const bf16x8*)(ap + 8);
                }
            }
            *(bf16x8*)(&As[srow * 64 + p0]) = v0;
            *(bf16x8*)(&As[srow * 64 + p1]) = v1;
        }
        {
            int gn = n0 + srow;
            const __bf16* bp = Wt + (size_t)gn * K + k0 + sq * 16;
            bf16x8 w0 = *(const bf16x8*)(bp);
            bf16x8 w1 = *(const bf16x8*)(bp + 8);
            *(bf16x8*)(&Bs[srow * 64 + p0]) = w0;
            *(bf16x8*)(&Bs[srow * 64 + p1]) = w1;
        }
        __syncthreads();
#pragma unroll
        for (int ks = 0; ks < 2; ks++) {
            bf16x8 a[2], b[2];
#pragma unroll
            for (int i = 0; i < 2; i++) {
                int ma = wr * 32 + i * 16 + fr;
                a[i] = *(const bf16x8*)(&As[ma * 64 + ((ks * 4 + gq) ^ (ma & 7)) * 8]);
                int nb = wc * 32 + i * 16 + fr;
                b[i] = *(const bf16x8*)(&Bs[nb * 64 + ((ks * 4 + gq) ^ (nb & 7)) * 8]);
            }
#pragma unroll
            for (int i = 0; i < 2; i++)
#pragma unroll
                for (int j = 0; j < 2; j++)
                    acc[i][j] = __builtin_amdgcn_mfma_f32_16x16x32_bf16(a[i], b[j], acc[i][j], 0, 0, 0);
        }
        __syncthreads();
    }
    int orow = gq * 4;
#pragma unroll
    for (int i = 0; i < 2; i++)
#pragma unroll
        for (int j = 0; j < 2; j++) {
            int gn = n0 + wc * 32 + j * 16 + fr;
            float bv = (gn < nsplit) ? bias[gn] : bias2[gn - nsplit];
#pragma unroll
            for (int r = 0; r < 4; r++) {
                int gm = m0 + wr * 32 + i * 16 + orow + r;
                if (gm < M) {
                    float v = acc[i][j][r] + bv;
                    if (RELU) v = fmaxf(v, 0.f);
                    stval(C + (size_t)gm * N + gn, v);
                }
            }
        }
}

__global__ void fillmark(float* o, int n, float v) {
    int i = blockIdx.x * blockDim.x + threadIdx.x;
    if (i < n) o[i] = v;
}

// ---------------- residual + layernorm ----------------
__global__ void ln_res(const float* a, const float* b,
                       const float* g, const float* be, float* o) {
    int row = blockIdx.x;
    int t = threadIdx.x;
    float x = a[(size_t)row * DD + t] + b[(size_t)row * DD + t];
    __shared__ float red[DD];
    red[t] = x;
    __syncthreads();
    for (int s = 128; s > 0; s >>= 1) {
        if (t < s) red[t] += red[t + s];
        __syncthreads();
    }
    float m = red[0] * (1.f / DD);
    __syncthreads();
    float d0 = x - m;
    red[t] = d0 * d0;
    __syncthreads();
    for (int s = 128; s > 0; s >>= 1) {
        if (t < s) red[t] += red[t + s];
        __syncthreads();
    }
    float v = red[0] * (1.f / DD);
    o[(size_t)row * DD + t] = d0 * rsqrtf(v + 1e-5f) * g[t] + be[t];
}

// ---------------- MFMA flash self-attention (QK packed, stride 512) ---------
#define QT 64
#define KT 64
#define NT ((NQQ + KT - 1) / KT)   // 15
#define QKLD 512

__global__ __launch_bounds__(256) void sa_attn_mfma(
    const __bf16* __restrict__ QK, const __bf16* __restrict__ V,
    float* __restrict__ O) {
    int blk = blockIdx.x;
    int tq = blk % NT;
    int bh = blk / NT;
    int h = bh % NH;
    int b = bh / NH;
    int tid = threadIdx.x;
    int lane = tid & 63;
    int wave = tid >> 6;
    int fr = lane & 15, gq = lane >> 4;
    int q0 = tq * QT;

    __shared__ __attribute__((aligned(16))) __bf16 Ks[KT][56];
    __shared__ __attribute__((aligned(16))) __bf16 Vt[HDIM][72];
    __shared__ __attribute__((aligned(16))) __bf16 Ps[4][16][72];

    int qrow = q0 + wave * 16 + fr;
    bf16x8 aq = {};
    if (qrow < NQQ)
        aq = *(const bf16x8*)(QK + ((size_t)(b * NQQ + qrow)) * QKLD + h * HDIM + gq * 8);

    f32x4 o0 = {}, o1 = {};
    float m_r[4] = {-1e30f, -1e30f, -1e30f, -1e30f};
    float l_r[4] = {0.f, 0.f, 0.f, 0.f};
    const float scale = 0.17677669529663687f;

    for (int kt = 0; kt < NT; kt++) {
        int kv0 = kt * KT;
        {
            int r = tid >> 2;
            int c8 = (tid & 3) * 8;
            int kvr = kv0 + r;
            bf16x8 kv_ = {}, vv_ = {};
            if (kvr < NQQ) {
                kv_ = *(const bf16x8*)(QK + ((size_t)(b * NQQ + kvr)) * QKLD + 256 + h * HDIM + c8);
                vv_ = *(const bf16x8*)(V + ((size_t)(b * NQQ + kvr)) * DD + h * HDIM + c8);
            }
            *(bf16x8*)(&Ks[r][c8]) = kv_;
#pragma unroll
            for (int j = 0; j < 8; j++) Vt[c8 + j][r] = vv_[j];
        }
        __syncthreads();

        f32x4 s[4];
#pragma unroll
        for (int f = 0; f < 4; f++) {
            bf16x8 bk = *(const bf16x8*)(&Ks[f * 16 + fr][gq * 8]);
            f32x4 z = {};
            s[f] = __builtin_amdgcn_mfma_f32_16x16x32_bf16(aq, bk, z, 0, 0, 0);
        }
#pragma unroll
        for (int f = 0; f < 4; f++) {
            bool valid = (kv0 + f * 16 + fr) < NQQ;
#pragma unroll
            for (int r = 0; r < 4; r++)
                s[f][r] = valid ? s[f][r] * scale : -1e30f;
        }
        float sc_[4];
#pragma unroll
        for (int r = 0; r < 4; r++) {
            float v = fmaxf(fmaxf(s[0][r], s[1][r]), fmaxf(s[2][r], s[3][r]));
            v = fmaxf(v, __shfl_xor(v, 1));
            v = fmaxf(v, __shfl_xor(v, 2));
            v = fmaxf(v, __shfl_xor(v, 4));
            v = fmaxf(v, __shfl_xor(v, 8));
            float mn = fmaxf(m_r[r], v);
            sc_[r] = expf(m_r[r] - mn);
            m_r[r] = mn;
        }
        float rs[4] = {0.f, 0.f, 0.f, 0.f};
#pragma unroll
        for (int f = 0; f < 4; f++)
#pragma unroll
            for (int r = 0; r < 4; r++) {
                float e = expf(s[f][r] - m_r[r]);
                s[f][r] = e;
                rs[r] += e;
            }
#pragma unroll
        for (int r = 0; r < 4; r++) {
            float v = rs[r];
            v += __shfl_xor(v, 1);
            v += __shfl_xor(v, 2);
            v += __shfl_xor(v, 4);
            v += __shfl_xor(v, 8);
            l_r[r] = l_r[r] * sc_[r] + v;
            o0[r] *= sc_[r];
            o1[r] *= sc_[r];
        }
#pragma unroll
        for (int f = 0; f < 4; f++)
#pragma unroll
            for (int r = 0; r < 4; r++)
                Ps[wave][gq * 4 + r][f * 16 + fr] = (__bf16)s[f][r];
#pragma unroll
        for (int c = 0; c < 2; c++) {
            bf16x8 ap = *(const bf16x8*)(&Ps[wave][fr][c * 32 + gq * 8]);
            bf16x8 bv0 = *(const bf16x8*)(&Vt[fr][c * 32 + gq * 8]);
            bf16x8 bv1 = *(const bf16x8*)(&Vt[16 + fr][c * 32 + gq * 8]);
            o0 = __builtin_amdgcn_mfma_f32_16x16x32_bf16(ap, bv0, o0, 0, 0, 0);
            o1 = __builtin_amdgcn_mfma_f32_16x16x32_bf16(ap, bv1, o1, 0, 0, 0);
        }
        __syncthreads();
    }
#pragma unroll
    for (int r = 0; r < 4; r++) {
        int qr = q0 + wave * 16 + gq * 4 + r;
        if (qr < NQQ) {
            float inv = 1.f / l_r[r];
            O[((size_t)(b * NQQ + qr)) * DD + h * HDIM + fr] = o0[r] * inv;
            O[((size_t)(b * NQQ + qr)) * DD + h * HDIM + 16 + fr] = o1[r] * inv;
        }
    }
}

// ---------------- msdeform v3: 1 query/block, 16B gathers, shfl reduce -------
// phase1 (tid<128): per-(h,lp) softmax weight + sample coords -> LDS
// phase2: tid=(h:8, dgrp:4, cpar:8); each thread 8 combos (lp,tap), bf16x8 tap
//         loads; reduce across the 8 consecutive lanes (cpar) via shfl_xor.
#define OAW 384

__global__ __launch_bounds__(256) void msdeform3(
    const __bf16* __restrict__ val, const __bf16* __restrict__ oa,
    const float* __restrict__ ref, float* __restrict__ out) {
    int tid = threadIdx.x;
    int row = blockIdx.x;               // flat b*NQQ+q
    int b_ = row / NQQ;

    __shared__ float sx[128], sy[128], sw[128];

    if (tid < 128) {
        int h = tid >> 4;
        int lp = tid & 15;
        int l = lp >> 2;
        float logit = (float)oa[(size_t)row * OAW + 256 + h * 16 + lp];
        float ox = (float)oa[(size_t)row * OAW + h * 32 + lp * 2];
        float oy = (float)oa[(size_t)row * OAW + h * 32 + lp * 2 + 1];
        const float* rp = ref + ((size_t)row * LV + l) * 4;
        float cx = rp[0], cy = rp[1], rw = rp[2], rh = rp[3];
        float mv = logit;
        mv = fmaxf(mv, __shfl_xor(mv, 1));
        mv = fmaxf(mv, __shfl_xor(mv, 2));
        mv = fmaxf(mv, __shfl_xor(mv, 4));
        mv = fmaxf(mv, __shfl_xor(mv, 8));
        float e = expf(logit - mv);
        float sum = e;
        sum += __shfl_xor(sum, 1);
        sum += __shfl_xor(sum, 2);
        sum += __shfl_xor(sum, 4);
        sum += __shfl_xor(sum, 8);
        int Wl = 128 >> l;
        float lx = cx + ox * (1.0f / NP) * rw * 0.5f;
        float ly = cy + oy * (1.0f / NP) * rh * 0.5f;
        sx[tid] = lx * Wl - 0.5f;
        sy[tid] = ly * Wl - 0.5f;       // H == W for all levels
        sw[tid] = e / sum;
    }
    __syncthreads();

    int cpar = tid & 7;
    int dgrp = (tid >> 3) & 3;
    int h = tid >> 5;
    const int stt[4] = {0, 16384, 20480, 21504};
    const __bf16* vb = val + (size_t)b_ * SS * DD + h * HDIM + dgrp * 8;
    float facc[8] = {};
#pragma unroll
    for (int k = 0; k < 8; k++) {
        int combo = cpar * 8 + k;       // 0..63 unique per (lp,tap)
        int lp = combo >> 2;
        int tap = combo & 3;
        int l = lp >> 2;
        int Wl = 128 >> l;
        int cidx = h * 16 + lp;
        float x = sx[cidx], y = sy[cidx], w = sw[cidx];
        float x0f = floorf(x), y0f = floorf(y);
        float dx = x - x0f, dy = y - y0f;
        int xi = (int)x0f + (tap & 1);
        int yi = (int)y0f + (tap >> 1);
        float wt = ((tap & 1) ? dx : 1.f - dx) * ((tap >> 1) ? dy : 1.f - dy) * w;
        if ((xi >= 0) & (xi < Wl) & (yi >= 0) & (yi < Wl)) {
            bf16x8 t = *(const bf16x8*)(vb + (size_t)(stt[l] + yi * Wl + xi) * DD);
#pragma unroll
            for (int e = 0; e < 8; e++) facc[e] += wt * (float)t[e];
        }
    }
    // reduce across the 8 cpar lanes (consecutive lanes of the same wave)
#pragma unroll
    for (int e = 0; e < 8; e++) {
        facc[e] += __shfl_xor(facc[e], 1);
        facc[e] += __shfl_xor(facc[e], 2);
        facc[e] += __shfl_xor(facc[e], 4);
    }
    // lane cpar writes element cpar -> out index == tid (coalesced)
    float v = facc[0];
#pragma unroll
    for (int e = 1; e < 8; e++) if (cpar == e) v = facc[e];
    out[(size_t)row * DD + tid] = v;
}

// ---------------- launch ----------------
extern "C" void kernel_launch(void* const* d_in, const int* in_sizes, int n_in,
                              void* d_out, int out_size, void* d_ws, size_t ws_size,
                              hipStream_t stream) {
    const float* query      = (const float*)d_in[0];
    const float* query_pos  = (const float*)d_in[1];
    const float* refpts     = (const float*)d_in[2];
    const float* input_flat = (const float*)d_in[3];
    const float* sa_in_w    = (const float*)d_in[6];
    const float* sa_in_b    = (const float*)d_in[7];
    const float* sa_out_w   = (const float*)d_in[8];
    const float* sa_out_b   = (const float*)d_in[9];
    const float* norm1_g    = (const float*)d_in[10];
    const float* norm1_b    = (const float*)d_in[11];
    const float* value_w    = (const float*)d_in[12];
    const float* value_b    = (const float*)d_in[13];
    const float* off_w      = (const float*)d_in[14];
    const float* off_b      = (const float*)d_in[15];
    const float* aw_w       = (const float*)d_in[16];
    const float* aw_b       = (const float*)d_in[17];
    const float* ca_out_w   = (const float*)d_in[18];
    const float* ca_out_b   = (const float*)d_in[19];
    const float* norm2_g    = (const float*)d_in[20];
    const float* norm2_b    = (const float*)d_in[21];
    const float* lin1_w     = (const float*)d_in[22];
    const float* lin1_b     = (const float*)d_in[23];
    const float* lin2_w     = (const float*)d_in[24];
    const float* lin2_b     = (const float*)d_in[25];
    const float* norm3_g    = (const float*)d_in[26];
    const float* norm3_b    = (const float*)d_in[27];
    float* out = (float*)d_out;

    const int M = BB * NQQ;              // 3600
    const int NE = M * DD;               // 921600
    const size_t slotBytes = (size_t)NE * 4;
    const size_t wElems = 6 * 65536 + 32768 + 65536 + 2 * 524288;
    const size_t wBytes = wElems * 2;
    const size_t bigBytes = (size_t)BB * SS * DD * 2;
    const size_t needBytes = 3 * slotBytes + wBytes + bigBytes;
    if (ws_size < needBytes) {
        float mark = 1000.0f + (float)(ws_size >> 20);
        fillmark<<<(out_size + 255) / 256, 256, 0, stream>>>(out, out_size, mark);
        return;
    }

    char* wsb = (char*)d_ws;
    float* s0 = (float*)(wsb);
    float* s1 = (float*)(wsb + slotBytes);
    float* s2 = (float*)(wsb + 2 * slotBytes);
    __bf16* wb = (__bf16*)(wsb + 3 * slotBytes);
    __bf16* vbig = (__bf16*)(wsb + 3 * slotBytes + wBytes);

    __bf16* wt_q   = wb;                 // [512][256] combined with wt_k
    __bf16* wt_k   = wb + 65536;
    __bf16* wt_v   = wb + 131072;
    __bf16* wt_sa  = wb + 196608;
    __bf16* wt_val = wb + 262144;
    __bf16* wt_off = wb + 327680;        // [384][256] combined with wt_aw
    __bf16* wt_aw  = wb + 393216;
    __bf16* wt_ca  = wb + 425984;
    __bf16* wt_l1  = wb + 491520;
    __bf16* wt_l2  = wb + 1015808;

    TPtrs tp;
    tp.s[0] = sa_in_w;          tp.d[0] = wt_q;
    tp.s[1] = sa_in_w + 65536;  tp.d[1] = wt_k;
    tp.s[2] = sa_in_w + 131072; tp.d[2] = wt_v;
    tp.s[3] = sa_out_w;         tp.d[3] = wt_sa;
    tp.s[4] = value_w;          tp.d[4] = wt_val;
    tp.s[5] = off_w;            tp.d[5] = wt_off;
    tp.s[6] = aw_w;             tp.d[6] = wt_aw;
    tp.s[7] = ca_out_w;         tp.d[7] = wt_ca;
    tp.s[8] = lin1_w;           tp.d[8] = wt_l1;
    tp.s[9] = lin2_w;           tp.d[9] = wt_l2;
    transp_all<<<1504, dim3(32, 8), 0, stream>>>(tp);

    __bf16* qkbuf = (__bf16*)s1;     // [M][512]
    __bf16* Vp = (__bf16*)s2;        // [M][256]
    __bf16* oabuf = (__bf16*)s1;     // [M][384] (after attn, qk dead)

    const int mt = (M + BM - 1) / BM;    // 57
    const int mtv = (BB * SS) / BM;      // 1360
    const int BIG = 1 << 30;

    // QK projection (fused +query_pos), N=512 -> s1
    mfma_gemm<float, __bf16, 0><<<dim3(8, mt), 256, 0, stream>>>(
        query, query_pos, wt_q, sa_in_b, sa_in_b, BIG, qkbuf, M, 512, DD);
    // V projection -> s2
    mfma_gemm<float, __bf16, 0><<<dim3(4, mt), 256, 0, stream>>>(
        query, nullptr, wt_v, sa_in_b + 512, sa_in_b, BIG, Vp, M, DD, DD);
    // attention -> s0
    sa_attn_mfma<<<BB * NH * NT, 256, 0, stream>>>(qkbuf, Vp, s0);
    // sa projection -> s1 (f32)
    mfma_gemm<float, float, 0><<<dim3(4, mt), 256, 0, stream>>>(
        s0, nullptr, wt_sa, sa_out_b, sa_out_b, BIG, s1, M, DD, DD);
    // x1 = LN(query + saproj) -> s2
    ln_res<<<M, DD, 0, stream>>>(query, s1, norm1_g, norm1_b, s2);
    // value projection -> vbig (bf16)
    mfma_gemm<float, __bf16, 0><<<dim3(4, mtv), 256, 0, stream>>>(
        input_flat, nullptr, wt_val, value_b, value_b, BIG, vbig, BB * SS, DD, DD);
    // off+aw projection (fused +query_pos), N=384 -> s1
    mfma_gemm<float, __bf16, 0><<<dim3(6, mt), 256, 0, stream>>>(
        s2, query_pos, wt_off, off_b, aw_b, 256, oabuf, M, OAW, DD);
    // deformable sampling -> s0
    msdeform3<<<M, 256, 0, stream>>>(vbig, oabuf, refpts, s0);
    // ca projection -> s1 (f32)
    mfma_gemm<float, float, 0><<<dim3(4, mt), 256, 0, stream>>>(
        s0, nullptr, wt_ca, ca_out_b, ca_out_b, BIG, s1, M, DD, DD);
    // x2 = LN(x1 + ca) -> s1
    ln_res<<<M, DD, 0, stream>>>(s2, s1, norm2_g, norm2_b, s1);
    // ffn1 -> vbig (bf16, relu)
    mfma_gemm<float, __bf16, 1><<<dim3(32, mt), 256, 0, stream>>>(
        s1, nullptr, wt_l1, lin1_b, lin1_b, BIG, vbig, M, DFF, DD);
    // ffn2 -> s0
    mfma_gemm<__bf16, float, 0><<<dim3(4, mt), 256, 0, stream>>>(
        vbig, nullptr, wt_l2, lin2_b, lin2_b, BIG, s0, M, DD, DFF);
    // out = LN(x2 + ffn2)
    ln_res<<<M, DD, 0, stream>>>(s1, s0, norm3_g, norm3_b, out);
}

// Round 8
// 220.166 us; speedup vs baseline: 9.9059x; 1.1102x over previous
//
#include <hip/hip_runtime.h>
#include <hip/hip_bf16.h>

#define DD   256
#define NH   8
#define HDIM 32
#define LV   4
#define NP   4
#define DFF  2048
#define BB   4
#define NQQ  900
#define SS   21760

typedef __bf16 bf16x8 __attribute__((ext_vector_type(8)));
typedef __bf16 bf16x2 __attribute__((ext_vector_type(2)));
typedef float  f32x4  __attribute__((ext_vector_type(4)));

__device__ inline void stval(float* p, float v) { *p = v; }
__device__ inline void stval(__bf16* p, float v) { *p = (__bf16)v; }

// ============ all weight transposes in ONE launch ============================
struct TPtrs {
    const float* s[10];
    __bf16* d[10];
};

__global__ void transp_all(TPtrs P) {
    const int Ks[10] = {256, 256, 256, 256, 256, 256, 256, 256, 256, 2048};
    const int Ns[10] = {256, 256, 256, 256, 256, 256, 128, 256, 2048, 256};
    const int tiles[10] = {64, 64, 64, 64, 64, 64, 32, 64, 512, 512};
    int t = blockIdx.x;
    int j = 0, base = 0;
    while (t >= base + tiles[j]) { base += tiles[j]; j++; }
    int lt = t - base;
    int K = Ks[j], N = Ns[j];
    int tn = N >> 5;
    int nb = (lt % tn) * 32, kb = (lt / tn) * 32;
    const float* W = P.s[j];
    __bf16* Wt = P.d[j];
    __shared__ float tbuf[32][33];
    for (int i = threadIdx.y; i < 32; i += 8)
        tbuf[i][threadIdx.x] = W[(size_t)(kb + i) * N + nb + threadIdx.x];
    __syncthreads();
    for (int i = threadIdx.y; i < 32; i += 8)
        Wt[(size_t)(nb + i) * K + kb + threadIdx.x] = (__bf16)tbuf[threadIdx.x][i];
}

// ============ MFMA GEMM: C = (A[+A2]) @ Wt^T + bias(split) ==================
// NSUB: number of 64-wide N-subtiles computed per block (A staged once).
#define BM 64
#define BN 64
#define BKK 64

template <typename AT, typename OT, int RELU, int NSUB>
__global__ __launch_bounds__(256) void mfma_gemm(
    const AT* __restrict__ A, const float* __restrict__ A2,
    const __bf16* __restrict__ Wt,
    const float* __restrict__ bias, const float* __restrict__ bias2, int nsplit,
    OT* __restrict__ C, int M, int N, int K) {
    int tid = threadIdx.x;
    int lane = tid & 63;
    int wave = tid >> 6;
    int wr = wave >> 1, wc = wave & 1;
    int m0 = blockIdx.y * BM;
    int n0 = blockIdx.x * (BN * NSUB);

    __shared__ __attribute__((aligned(16))) __bf16 As[BM * BKK];
    __shared__ __attribute__((aligned(16))) __bf16 Bs[NSUB][BN * BKK];

    f32x4 acc[NSUB][2][2] = {};

    int srow = tid >> 2;
    int sq = tid & 3;
    int u0 = sq << 1;
    int p0 = (u0 ^ (srow & 7)) * 8;
    int p1 = ((u0 + 1) ^ (srow & 7)) * 8;
    int fr = lane & 15, gq = lane >> 4;

    for (int k0 = 0; k0 < K; k0 += BKK) {
        {
            int gm = m0 + srow;
            bf16x8 v0 = {}, v1 = {};
            if (gm < M) {
                if constexpr (sizeof(AT) == 4) {
                    const float* ap = (const float*)A + (size_t)gm * K + k0 + sq * 16;
                    f32x4 f0 = *(const f32x4*)(ap + 0);
                    f32x4 f1 = *(const f32x4*)(ap + 4);
                    f32x4 f2 = *(const f32x4*)(ap + 8);
                    f32x4 f3 = *(const f32x4*)(ap + 12);
                    if (A2) {
                        const float* ap2 = A2 + (size_t)gm * K + k0 + sq * 16;
                        f0 += *(const f32x4*)(ap2 + 0);
                        f1 += *(const f32x4*)(ap2 + 4);
                        f2 += *(const f32x4*)(ap2 + 8);
                        f3 += *(const f32x4*)(ap2 + 12);
                    }
#pragma unroll
                    for (int e = 0; e < 4; e++) {
                        v0[e] = (__bf16)f0[e]; v0[e + 4] = (__bf16)f1[e];
                        v1[e] = (__bf16)f2[e]; v1[e + 4] = (__bf16)f3[e];
                    }
                } else {
                    const __bf16* ap = (const __bf16*)A + (size_t)gm * K + k0 + sq * 16;
                    v0 = *(const bf16x8*)(ap);
                    v1 = *(const bf16x8*)(ap + 8);
                }
            }
            *(bf16x8*)(&As[srow * 64 + p0]) = v0;
            *(bf16x8*)(&As[srow * 64 + p1]) = v1;
        }
#pragma unroll
        for (int ns = 0; ns < NSUB; ns++) {
            int gn = n0 + ns * BN + srow;
            const __bf16* bp = Wt + (size_t)gn * K + k0 + sq * 16;
            bf16x8 w0 = *(const bf16x8*)(bp);
            bf16x8 w1 = *(const bf16x8*)(bp + 8);
            *(bf16x8*)(&Bs[ns][srow * 64 + p0]) = w0;
            *(bf16x8*)(&Bs[ns][srow * 64 + p1]) = w1;
        }
        __syncthreads();
#pragma unroll
        for (int ks = 0; ks < 2; ks++) {
            bf16x8 a[2];
#pragma unroll
            for (int i = 0; i < 2; i++) {
                int ma = wr * 32 + i * 16 + fr;
                a[i] = *(const bf16x8*)(&As[ma * 64 + ((ks * 4 + gq) ^ (ma & 7)) * 8]);
            }
#pragma unroll
            for (int ns = 0; ns < NSUB; ns++) {
                bf16x8 b[2];
#pragma unroll
                for (int j = 0; j < 2; j++) {
                    int nb = wc * 32 + j * 16 + fr;
                    b[j] = *(const bf16x8*)(&Bs[ns][nb * 64 + ((ks * 4 + gq) ^ (nb & 7)) * 8]);
                }
#pragma unroll
                for (int i = 0; i < 2; i++)
#pragma unroll
                    for (int j = 0; j < 2; j++)
                        acc[ns][i][j] = __builtin_amdgcn_mfma_f32_16x16x32_bf16(a[i], b[j], acc[ns][i][j], 0, 0, 0);
            }
        }
        __syncthreads();
    }
    int orow = gq * 4;
#pragma unroll
    for (int ns = 0; ns < NSUB; ns++)
#pragma unroll
        for (int i = 0; i < 2; i++)
#pragma unroll
            for (int j = 0; j < 2; j++) {
                int gn = n0 + ns * BN + wc * 32 + j * 16 + fr;
                float bv = (gn < nsplit) ? bias[gn] : bias2[gn - nsplit];
#pragma unroll
                for (int r = 0; r < 4; r++) {
                    int gm = m0 + wr * 32 + i * 16 + orow + r;
                    if (gm < M) {
                        float v = acc[ns][i][j][r] + bv;
                        if (RELU) v = fmaxf(v, 0.f);
                        stval(C + (size_t)gm * N + gn, v);
                    }
                }
            }
}

__global__ void fillmark(float* o, int n, float v) {
    int i = blockIdx.x * blockDim.x + threadIdx.x;
    if (i < n) o[i] = v;
}

// ---------------- residual + layernorm ----------------
__global__ void ln_res(const float* a, const float* b,
                       const float* g, const float* be, float* o) {
    int row = blockIdx.x;
    int t = threadIdx.x;
    float x = a[(size_t)row * DD + t] + b[(size_t)row * DD + t];
    __shared__ float red[DD];
    red[t] = x;
    __syncthreads();
    for (int s = 128; s > 0; s >>= 1) {
        if (t < s) red[t] += red[t + s];
        __syncthreads();
    }
    float m = red[0] * (1.f / DD);
    __syncthreads();
    float d0 = x - m;
    red[t] = d0 * d0;
    __syncthreads();
    for (int s = 128; s > 0; s >>= 1) {
        if (t < s) red[t] += red[t + s];
        __syncthreads();
    }
    float v = red[0] * (1.f / DD);
    o[(size_t)row * DD + t] = d0 * rsqrtf(v + 1e-5f) * g[t] + be[t];
}

// ---------------- MFMA flash self-attention (QK packed, stride 512) ---------
#define QT 64
#define KT 64
#define NT ((NQQ + KT - 1) / KT)   // 15
#define QKLD 512

__global__ __launch_bounds__(256) void sa_attn_mfma(
    const __bf16* __restrict__ QK, const __bf16* __restrict__ V,
    float* __restrict__ O) {
    int blk = blockIdx.x;
    int tq = blk % NT;
    int bh = blk / NT;
    int h = bh % NH;
    int b = bh / NH;
    int tid = threadIdx.x;
    int lane = tid & 63;
    int wave = tid >> 6;
    int fr = lane & 15, gq = lane >> 4;
    int q0 = tq * QT;

    __shared__ __attribute__((aligned(16))) __bf16 Ks[KT][56];
    __shared__ __attribute__((aligned(16))) __bf16 Vt[HDIM][72];
    __shared__ __attribute__((aligned(16))) __bf16 Ps[4][16][72];

    int qrow = q0 + wave * 16 + fr;
    bf16x8 aq = {};
    if (qrow < NQQ)
        aq = *(const bf16x8*)(QK + ((size_t)(b * NQQ + qrow)) * QKLD + h * HDIM + gq * 8);

    f32x4 o0 = {}, o1 = {};
    float m_r[4] = {-1e30f, -1e30f, -1e30f, -1e30f};
    float l_r[4] = {0.f, 0.f, 0.f, 0.f};
    const float scale = 0.17677669529663687f;

    for (int kt = 0; kt < NT; kt++) {
        int kv0 = kt * KT;
        {
            int r = tid >> 2;
            int c8 = (tid & 3) * 8;
            int kvr = kv0 + r;
            bf16x8 kv_ = {}, vv_ = {};
            if (kvr < NQQ) {
                kv_ = *(const bf16x8*)(QK + ((size_t)(b * NQQ + kvr)) * QKLD + 256 + h * HDIM + c8);
                vv_ = *(const bf16x8*)(V + ((size_t)(b * NQQ + kvr)) * DD + h * HDIM + c8);
            }
            *(bf16x8*)(&Ks[r][c8]) = kv_;
#pragma unroll
            for (int j = 0; j < 8; j++) Vt[c8 + j][r] = vv_[j];
        }
        __syncthreads();

        f32x4 s[4];
#pragma unroll
        for (int f = 0; f < 4; f++) {
            bf16x8 bk = *(const bf16x8*)(&Ks[f * 16 + fr][gq * 8]);
            f32x4 z = {};
            s[f] = __builtin_amdgcn_mfma_f32_16x16x32_bf16(aq, bk, z, 0, 0, 0);
        }
#pragma unroll
        for (int f = 0; f < 4; f++) {
            bool valid = (kv0 + f * 16 + fr) < NQQ;
#pragma unroll
            for (int r = 0; r < 4; r++)
                s[f][r] = valid ? s[f][r] * scale : -1e30f;
        }
        float sc_[4];
#pragma unroll
        for (int r = 0; r < 4; r++) {
            float v = fmaxf(fmaxf(s[0][r], s[1][r]), fmaxf(s[2][r], s[3][r]));
            v = fmaxf(v, __shfl_xor(v, 1));
            v = fmaxf(v, __shfl_xor(v, 2));
            v = fmaxf(v, __shfl_xor(v, 4));
            v = fmaxf(v, __shfl_xor(v, 8));
            float mn = fmaxf(m_r[r], v);
            sc_[r] = expf(m_r[r] - mn);
            m_r[r] = mn;
        }
        float rs[4] = {0.f, 0.f, 0.f, 0.f};
#pragma unroll
        for (int f = 0; f < 4; f++)
#pragma unroll
            for (int r = 0; r < 4; r++) {
                float e = expf(s[f][r] - m_r[r]);
                s[f][r] = e;
                rs[r] += e;
            }
#pragma unroll
        for (int r = 0; r < 4; r++) {
            float v = rs[r];
            v += __shfl_xor(v, 1);
            v += __shfl_xor(v, 2);
            v += __shfl_xor(v, 4);
            v += __shfl_xor(v, 8);
            l_r[r] = l_r[r] * sc_[r] + v;
            o0[r] *= sc_[r];
            o1[r] *= sc_[r];
        }
#pragma unroll
        for (int f = 0; f < 4; f++)
#pragma unroll
            for (int r = 0; r < 4; r++)
                Ps[wave][gq * 4 + r][f * 16 + fr] = (__bf16)s[f][r];
#pragma unroll
        for (int c = 0; c < 2; c++) {
            bf16x8 ap = *(const bf16x8*)(&Ps[wave][fr][c * 32 + gq * 8]);
            bf16x8 bv0 = *(const bf16x8*)(&Vt[fr][c * 32 + gq * 8]);
            bf16x8 bv1 = *(const bf16x8*)(&Vt[16 + fr][c * 32 + gq * 8]);
            o0 = __builtin_amdgcn_mfma_f32_16x16x32_bf16(ap, bv0, o0, 0, 0, 0);
            o1 = __builtin_amdgcn_mfma_f32_16x16x32_bf16(ap, bv1, o1, 0, 0, 0);
        }
        __syncthreads();
    }
#pragma unroll
    for (int r = 0; r < 4; r++) {
        int qr = q0 + wave * 16 + gq * 4 + r;
        if (qr < NQQ) {
            float inv = 1.f / l_r[r];
            O[((size_t)(b * NQQ + qr)) * DD + h * HDIM + fr] = o0[r] * inv;
            O[((size_t)(b * NQQ + qr)) * DD + h * HDIM + 16 + fr] = o1[r] * inv;
        }
    }
}

// ---------------- msdeform v3: 1 query/block, 16B gathers, shfl reduce -------
#define OAW 384

__global__ __launch_bounds__(256) void msdeform3(
    const __bf16* __restrict__ val, const __bf16* __restrict__ oa,
    const float* __restrict__ ref, float* __restrict__ out) {
    int tid = threadIdx.x;
    int row = blockIdx.x;               // flat b*NQQ+q
    int b_ = row / NQQ;

    __shared__ float sx[128], sy[128], sw[128];

    if (tid < 128) {
        int h = tid >> 4;
        int lp = tid & 15;
        int l = lp >> 2;
        float logit = (float)oa[(size_t)row * OAW + 256 + h * 16 + lp];
        float ox = (float)oa[(size_t)row * OAW + h * 32 + lp * 2];
        float oy = (float)oa[(size_t)row * OAW + h * 32 + lp * 2 + 1];
        const float* rp = ref + ((size_t)row * LV + l) * 4;
        float cx = rp[0], cy = rp[1], rw = rp[2], rh = rp[3];
        float mv = logit;
        mv = fmaxf(mv, __shfl_xor(mv, 1));
        mv = fmaxf(mv, __shfl_xor(mv, 2));
        mv = fmaxf(mv, __shfl_xor(mv, 4));
        mv = fmaxf(mv, __shfl_xor(mv, 8));
        float e = expf(logit - mv);
        float sum = e;
        sum += __shfl_xor(sum, 1);
        sum += __shfl_xor(sum, 2);
        sum += __shfl_xor(sum, 4);
        sum += __shfl_xor(sum, 8);
        int Wl = 128 >> l;
        float lx = cx + ox * (1.0f / NP) * rw * 0.5f;
        float ly = cy + oy * (1.0f / NP) * rh * 0.5f;
        sx[tid] = lx * Wl - 0.5f;
        sy[tid] = ly * Wl - 0.5f;       // H == W for all levels
        sw[tid] = e / sum;
    }
    __syncthreads();

    int cpar = tid & 7;
    int dgrp = (tid >> 3) & 3;
    int h = tid >> 5;
    const int stt[4] = {0, 16384, 20480, 21504};
    const __bf16* vb = val + (size_t)b_ * SS * DD + h * HDIM + dgrp * 8;
    float facc[8] = {};
#pragma unroll
    for (int k = 0; k < 8; k++) {
        int combo = cpar * 8 + k;       // 0..63 unique per (lp,tap)
        int lp = combo >> 2;
        int tap = combo & 3;
        int l = lp >> 2;
        int Wl = 128 >> l;
        int cidx = h * 16 + lp;
        float x = sx[cidx], y = sy[cidx], w = sw[cidx];
        float x0f = floorf(x), y0f = floorf(y);
        float dx = x - x0f, dy = y - y0f;
        int xi = (int)x0f + (tap & 1);
        int yi = (int)y0f + (tap >> 1);
        float wt = ((tap & 1) ? dx : 1.f - dx) * ((tap >> 1) ? dy : 1.f - dy) * w;
        if ((xi >= 0) & (xi < Wl) & (yi >= 0) & (yi < Wl)) {
            bf16x8 t = *(const bf16x8*)(vb + (size_t)(stt[l] + yi * Wl + xi) * DD);
#pragma unroll
            for (int e = 0; e < 8; e++) facc[e] += wt * (float)t[e];
        }
    }
#pragma unroll
    for (int e = 0; e < 8; e++) {
        facc[e] += __shfl_xor(facc[e], 1);
        facc[e] += __shfl_xor(facc[e], 2);
        facc[e] += __shfl_xor(facc[e], 4);
    }
    float v = facc[0];
#pragma unroll
    for (int e = 1; e < 8; e++) if (cpar == e) v = facc[e];
    out[(size_t)row * DD + tid] = v;
}

// ---------------- launch ----------------
extern "C" void kernel_launch(void* const* d_in, const int* in_sizes, int n_in,
                              void* d_out, int out_size, void* d_ws, size_t ws_size,
                              hipStream_t stream) {
    const float* query      = (const float*)d_in[0];
    const float* query_pos  = (const float*)d_in[1];
    const float* refpts     = (const float*)d_in[2];
    const float* input_flat = (const float*)d_in[3];
    const float* sa_in_w    = (const float*)d_in[6];
    const float* sa_in_b    = (const float*)d_in[7];
    const float* sa_out_w   = (const float*)d_in[8];
    const float* sa_out_b   = (const float*)d_in[9];
    const float* norm1_g    = (const float*)d_in[10];
    const float* norm1_b    = (const float*)d_in[11];
    const float* value_w    = (const float*)d_in[12];
    const float* value_b    = (const float*)d_in[13];
    const float* off_w      = (const float*)d_in[14];
    const float* off_b      = (const float*)d_in[15];
    const float* aw_w       = (const float*)d_in[16];
    const float* aw_b       = (const float*)d_in[17];
    const float* ca_out_w   = (const float*)d_in[18];
    const float* ca_out_b   = (const float*)d_in[19];
    const float* norm2_g    = (const float*)d_in[20];
    const float* norm2_b    = (const float*)d_in[21];
    const float* lin1_w     = (const float*)d_in[22];
    const float* lin1_b     = (const float*)d_in[23];
    const float* lin2_w     = (const float*)d_in[24];
    const float* lin2_b     = (const float*)d_in[25];
    const float* norm3_g    = (const float*)d_in[26];
    const float* norm3_b    = (const float*)d_in[27];
    float* out = (float*)d_out;

    const int M = BB * NQQ;              // 3600
    const int NE = M * DD;               // 921600
    const size_t slotBytes = (size_t)NE * 4;
    const size_t wElems = 6 * 65536 + 32768 + 65536 + 2 * 524288;
    const size_t wBytes = wElems * 2;
    const size_t bigBytes = (size_t)BB * SS * DD * 2;
    const size_t needBytes = 3 * slotBytes + wBytes + bigBytes;
    if (ws_size < needBytes) {
        float mark = 1000.0f + (float)(ws_size >> 20);
        fillmark<<<(out_size + 255) / 256, 256, 0, stream>>>(out, out_size, mark);
        return;
    }

    char* wsb = (char*)d_ws;
    float* s0 = (float*)(wsb);
    float* s1 = (float*)(wsb + slotBytes);
    float* s2 = (float*)(wsb + 2 * slotBytes);
    __bf16* wb = (__bf16*)(wsb + 3 * slotBytes);
    __bf16* vbig = (__bf16*)(wsb + 3 * slotBytes + wBytes);

    __bf16* wt_q   = wb;                 // [512][256] combined with wt_k
    __bf16* wt_k   = wb + 65536;
    __bf16* wt_v   = wb + 131072;
    __bf16* wt_sa  = wb + 196608;
    __bf16* wt_val = wb + 262144;
    __bf16* wt_off = wb + 327680;        // [384][256] combined with wt_aw
    __bf16* wt_aw  = wb + 393216;
    __bf16* wt_ca  = wb + 425984;
    __bf16* wt_l1  = wb + 491520;
    __bf16* wt_l2  = wb + 1015808;

    TPtrs tp;
    tp.s[0] = sa_in_w;          tp.d[0] = wt_q;
    tp.s[1] = sa_in_w + 65536;  tp.d[1] = wt_k;
    tp.s[2] = sa_in_w + 131072; tp.d[2] = wt_v;
    tp.s[3] = sa_out_w;         tp.d[3] = wt_sa;
    tp.s[4] = value_w;          tp.d[4] = wt_val;
    tp.s[5] = off_w;            tp.d[5] = wt_off;
    tp.s[6] = aw_w;             tp.d[6] = wt_aw;
    tp.s[7] = ca_out_w;         tp.d[7] = wt_ca;
    tp.s[8] = lin1_w;           tp.d[8] = wt_l1;
    tp.s[9] = lin2_w;           tp.d[9] = wt_l2;
    transp_all<<<1504, dim3(32, 8), 0, stream>>>(tp);

    __bf16* qkbuf = (__bf16*)s1;     // [M][512]
    __bf16* Vp = (__bf16*)s2;        // [M][256]
    __bf16* oabuf = (__bf16*)s1;     // [M][384] (after attn, qk dead)

    const int mt = (M + BM - 1) / BM;    // 57
    const int mtv = (BB * SS) / BM;      // 1360
    const int BIG = 1 << 30;

    // QK projection (fused +query_pos), N=512 -> s1
    mfma_gemm<float, __bf16, 0, 1><<<dim3(8, mt), 256, 0, stream>>>(
        query, query_pos, wt_q, sa_in_b, sa_in_b, BIG, qkbuf, M, 512, DD);
    // V projection -> s2
    mfma_gemm<float, __bf16, 0, 1><<<dim3(4, mt), 256, 0, stream>>>(
        query, nullptr, wt_v, sa_in_b + 512, sa_in_b, BIG, Vp, M, DD, DD);
    // attention -> s0
    sa_attn_mfma<<<BB * NH * NT, 256, 0, stream>>>(qkbuf, Vp, s0);
    // sa projection -> s1 (f32)
    mfma_gemm<float, float, 0, 1><<<dim3(4, mt), 256, 0, stream>>>(
        s0, nullptr, wt_sa, sa_out_b, sa_out_b, BIG, s1, M, DD, DD);
    // x1 = LN(query + saproj) -> s2
    ln_res<<<M, DD, 0, stream>>>(query, s1, norm1_g, norm1_b, s2);
    // value projection -> vbig (bf16); NSUB=4 so A is fetched once
    mfma_gemm<float, __bf16, 0, 4><<<dim3(1, mtv), 256, 0, stream>>>(
        input_flat, nullptr, wt_val, value_b, value_b, BIG, vbig, BB * SS, DD, DD);
    // off+aw projection (fused +query_pos), N=384 -> s1
    mfma_gemm<float, __bf16, 0, 1><<<dim3(6, mt), 256, 0, stream>>>(
        s2, query_pos, wt_off, off_b, aw_b, 256, oabuf, M, OAW, DD);
    // deformable sampling -> s0
    msdeform3<<<M, 256, 0, stream>>>(vbig, oabuf, refpts, s0);
    // ca projection -> s1 (f32)
    mfma_gemm<float, float, 0, 1><<<dim3(4, mt), 256, 0, stream>>>(
        s0, nullptr, wt_ca, ca_out_b, ca_out_b, BIG, s1, M, DD, DD);
    // x2 = LN(x1 + ca) -> s1
    ln_res<<<M, DD, 0, stream>>>(s2, s1, norm2_g, norm2_b, s1);
    // ffn1 -> vbig (bf16, relu)
    mfma_gemm<float, __bf16, 1, 1><<<dim3(32, mt), 256, 0, stream>>>(
        s1, nullptr, wt_l1, lin1_b, lin1_b, BIG, vbig, M, DFF, DD);
    // ffn2 -> s0
    mfma_gemm<__bf16, float, 0, 1><<<dim3(4, mt), 256, 0, stream>>>(
        vbig, nullptr, wt_l2, lin2_b, lin2_b, BIG, s0, M, DD, DFF);
    // out = LN(x2 + ffn2)
    ln_res<<<M, DD, 0, stream>>>(s1, s0, norm3_g, norm3_b, out);
}

// Round 9
// 217.003 us; speedup vs baseline: 10.0503x; 1.0146x over previous
//
#include <hip/hip_runtime.h>
#include <hip/hip_bf16.h>

#define DD   256
#define NH   8
#define HDIM 32
#define LV   4
#define NP   4
#define DFF  2048
#define BB   4
#define NQQ  900
#define SS   21760

typedef __bf16 bf16x8 __attribute__((ext_vector_type(8)));
typedef __bf16 bf16x2 __attribute__((ext_vector_type(2)));
typedef float  f32x4  __attribute__((ext_vector_type(4)));

__device__ inline void stval(float* p, float v) { *p = v; }
__device__ inline void stval(__bf16* p, float v) { *p = (__bf16)v; }

__device__ __forceinline__ void gload16(const void* g, void* l) {
    __builtin_amdgcn_global_load_lds(
        (const __attribute__((address_space(1))) void*)g,
        (__attribute__((address_space(3))) void*)l, 16, 0, 0);
}

// ============ all weight transposes in ONE launch ============================
struct TPtrs {
    const float* s[10];
    __bf16* d[10];
};

__global__ void transp_all(TPtrs P) {
    const int Ks[10] = {256, 256, 256, 256, 256, 256, 256, 256, 256, 2048};
    const int Ns[10] = {256, 256, 256, 256, 256, 256, 128, 256, 2048, 256};
    const int tiles[10] = {64, 64, 64, 64, 64, 64, 32, 64, 512, 512};
    int t = blockIdx.x;
    int j = 0, base = 0;
    while (t >= base + tiles[j]) { base += tiles[j]; j++; }
    int lt = t - base;
    int K = Ks[j], N = Ns[j];
    int tn = N >> 5;
    int nb = (lt % tn) * 32, kb = (lt / tn) * 32;
    const float* W = P.s[j];
    __bf16* Wt = P.d[j];
    __shared__ float tbuf[32][33];
    for (int i = threadIdx.y; i < 32; i += 8)
        tbuf[i][threadIdx.x] = W[(size_t)(kb + i) * N + nb + threadIdx.x];
    __syncthreads();
    for (int i = threadIdx.y; i < 32; i += 8)
        Wt[(size_t)(nb + i) * K + kb + threadIdx.x] = (__bf16)tbuf[threadIdx.x][i];
}

// ============ MFMA GEMM: C = (A[+A2]) @ Wt^T + bias(split) ==================
#define BM 64
#define BN 64
#define BKK 64

template <typename AT, typename OT, int RELU, int NSUB>
__global__ __launch_bounds__(256) void mfma_gemm(
    const AT* __restrict__ A, const float* __restrict__ A2,
    const __bf16* __restrict__ Wt,
    const float* __restrict__ bias, const float* __restrict__ bias2, int nsplit,
    OT* __restrict__ C, int M, int N, int K) {
    int tid = threadIdx.x;
    int lane = tid & 63;
    int wave = tid >> 6;
    int wr = wave >> 1, wc = wave & 1;
    int m0 = blockIdx.y * BM;
    int n0 = blockIdx.x * (BN * NSUB);

    __shared__ __attribute__((aligned(16))) __bf16 As[BM * BKK];
    __shared__ __attribute__((aligned(16))) __bf16 Bs[NSUB][BN * BKK];

    f32x4 acc[NSUB][2][2] = {};

    int srow = tid >> 2;
    int sq = tid & 3;
    int u0 = sq << 1;
    int p0 = (u0 ^ (srow & 7)) * 8;
    int p1 = ((u0 + 1) ^ (srow & 7)) * 8;
    int fr = lane & 15, gq = lane >> 4;

    for (int k0 = 0; k0 < K; k0 += BKK) {
        {
            int gm = m0 + srow;
            bf16x8 v0 = {}, v1 = {};
            if (gm < M) {
                if constexpr (sizeof(AT) == 4) {
                    const float* ap = (const float*)A + (size_t)gm * K + k0 + sq * 16;
                    f32x4 f0 = *(const f32x4*)(ap + 0);
                    f32x4 f1 = *(const f32x4*)(ap + 4);
                    f32x4 f2 = *(const f32x4*)(ap + 8);
                    f32x4 f3 = *(const f32x4*)(ap + 12);
                    if (A2) {
                        const float* ap2 = A2 + (size_t)gm * K + k0 + sq * 16;
                        f0 += *(const f32x4*)(ap2 + 0);
                        f1 += *(const f32x4*)(ap2 + 4);
                        f2 += *(const f32x4*)(ap2 + 8);
                        f3 += *(const f32x4*)(ap2 + 12);
                    }
#pragma unroll
                    for (int e = 0; e < 4; e++) {
                        v0[e] = (__bf16)f0[e]; v0[e + 4] = (__bf16)f1[e];
                        v1[e] = (__bf16)f2[e]; v1[e + 4] = (__bf16)f3[e];
                    }
                } else {
                    const __bf16* ap = (const __bf16*)A + (size_t)gm * K + k0 + sq * 16;
                    v0 = *(const bf16x8*)(ap);
                    v1 = *(const bf16x8*)(ap + 8);
                }
            }
            *(bf16x8*)(&As[srow * 64 + p0]) = v0;
            *(bf16x8*)(&As[srow * 64 + p1]) = v1;
        }
#pragma unroll
        for (int ns = 0; ns < NSUB; ns++) {
            int gn = n0 + ns * BN + srow;
            const __bf16* bp = Wt + (size_t)gn * K + k0 + sq * 16;
            bf16x8 w0 = *(const bf16x8*)(bp);
            bf16x8 w1 = *(const bf16x8*)(bp + 8);
            *(bf16x8*)(&Bs[ns][srow * 64 + p0]) = w0;
            *(bf16x8*)(&Bs[ns][srow * 64 + p1]) = w1;
        }
        __syncthreads();
#pragma unroll
        for (int ks = 0; ks < 2; ks++) {
            bf16x8 a[2];
#pragma unroll
            for (int i = 0; i < 2; i++) {
                int ma = wr * 32 + i * 16 + fr;
                a[i] = *(const bf16x8*)(&As[ma * 64 + ((ks * 4 + gq) ^ (ma & 7)) * 8]);
            }
#pragma unroll
            for (int ns = 0; ns < NSUB; ns++) {
                bf16x8 b[2];
#pragma unroll
                for (int j = 0; j < 2; j++) {
                    int nb = wc * 32 + j * 16 + fr;
                    b[j] = *(const bf16x8*)(&Bs[ns][nb * 64 + ((ks * 4 + gq) ^ (nb & 7)) * 8]);
                }
#pragma unroll
                for (int i = 0; i < 2; i++)
#pragma unroll
                    for (int j = 0; j < 2; j++)
                        acc[ns][i][j] = __builtin_amdgcn_mfma_f32_16x16x32_bf16(a[i], b[j], acc[ns][i][j], 0, 0, 0);
            }
        }
        __syncthreads();
    }
    int orow = gq * 4;
#pragma unroll
    for (int ns = 0; ns < NSUB; ns++)
#pragma unroll
        for (int i = 0; i < 2; i++)
#pragma unroll
            for (int j = 0; j < 2; j++) {
                int gn = n0 + ns * BN + wc * 32 + j * 16 + fr;
                float bv = (gn < nsplit) ? bias[gn] : bias2[gn - nsplit];
#pragma unroll
                for (int r = 0; r < 4; r++) {
                    int gm = m0 + wr * 32 + i * 16 + orow + r;
                    if (gm < M) {
                        float v = acc[ns][i][j][r] + bv;
                        if (RELU) v = fmaxf(v, 0.f);
                        stval(C + (size_t)gm * N + gn, v);
                    }
                }
            }
}

// ============ value GEMM: [87040x256] x [256x256], double-buffered ==========
// A f32 reg-staged (issue-early), B via global_load_lds (pre-swizzled source).
__global__ __launch_bounds__(256) void value_gemm(
    const float* __restrict__ A, const __bf16* __restrict__ Wt,
    const float* __restrict__ bias, __bf16* __restrict__ C) {
    int tid = threadIdx.x;
    int lane = tid & 63;
    int wave = tid >> 6;
    int wr = wave >> 1, wc = wave & 1;
    int m0 = blockIdx.x * 64;

    __shared__ __attribute__((aligned(16))) __bf16 As[2][64 * 64];
    __shared__ __attribute__((aligned(16))) __bf16 Bs[2][4][64 * 64];

    f32x4 acc[4][2][2] = {};

    int srow = tid >> 2;
    int sq = tid & 3;
    int u0 = sq << 1;
    int p0 = (u0 ^ (srow & 7)) * 8;
    int p1 = ((u0 + 1) ^ (srow & 7)) * 8;
    int fr = lane & 15, gq = lane >> 4;

    // B staging geometry: wave stages ns=wave; chunk c covers rows c*8..c*8+7.
    // lane: row_in_chunk = lane>>3, 16B-unit = lane&7; LDS pos (row,u) must hold
    // global unit u^(row&7); row&7 == lane>>3 here.
    int c_row = lane >> 3;
    int c_u = lane & 7;
    int gu = c_u ^ c_row;
    const __bf16* bsrc0 = Wt + (size_t)(wave * 64 + c_row) * 256 + gu * 8;

    const float* aptr = A + (size_t)(m0 + srow) * 256 + sq * 16;

    // ---- prologue: stage step 0 into buf 0 ----
    f32x4 fa0 = *(const f32x4*)(aptr + 0);
    f32x4 fa1 = *(const f32x4*)(aptr + 4);
    f32x4 fa2 = *(const f32x4*)(aptr + 8);
    f32x4 fa3 = *(const f32x4*)(aptr + 12);
#pragma unroll
    for (int c = 0; c < 8; c++)
        gload16(bsrc0 + (size_t)c * 8 * 256, &Bs[0][wave][c * 512]);
    {
        bf16x8 v0, v1;
#pragma unroll
        for (int e = 0; e < 4; e++) {
            v0[e] = (__bf16)fa0[e]; v0[e + 4] = (__bf16)fa1[e];
            v1[e] = (__bf16)fa2[e]; v1[e + 4] = (__bf16)fa3[e];
        }
        *(bf16x8*)(&As[0][srow * 64 + p0]) = v0;
        *(bf16x8*)(&As[0][srow * 64 + p1]) = v1;
    }
    __syncthreads();

    for (int step = 0; step < 4; step++) {
        int p = step & 1;
        if (step < 3) {
            // issue next-tile A loads FIRST (so their wait leaves B in flight)
            const float* ap2 = aptr + (step + 1) * 64;
            fa0 = *(const f32x4*)(ap2 + 0);
            fa1 = *(const f32x4*)(ap2 + 4);
            fa2 = *(const f32x4*)(ap2 + 8);
            fa3 = *(const f32x4*)(ap2 + 12);
            const __bf16* bsrc = bsrc0 + (step + 1) * 64;
#pragma unroll
            for (int c = 0; c < 8; c++)
                gload16(bsrc + (size_t)c * 8 * 256, &Bs[p ^ 1][wave][c * 512]);
        }
#pragma unroll
        for (int ks = 0; ks < 2; ks++) {
            bf16x8 a[2];
#pragma unroll
            for (int i = 0; i < 2; i++) {
                int ma = wr * 32 + i * 16 + fr;
                a[i] = *(const bf16x8*)(&As[p][ma * 64 + ((ks * 4 + gq) ^ (ma & 7)) * 8]);
            }
#pragma unroll
            for (int ns = 0; ns < 4; ns++) {
                bf16x8 b[2];
#pragma unroll
                for (int j = 0; j < 2; j++) {
                    int nb = wc * 32 + j * 16 + fr;
                    b[j] = *(const bf16x8*)(&Bs[p][ns][nb * 64 + ((ks * 4 + gq) ^ (nb & 7)) * 8]);
                }
#pragma unroll
                for (int i = 0; i < 2; i++)
#pragma unroll
                    for (int j = 0; j < 2; j++)
                        acc[ns][i][j] = __builtin_amdgcn_mfma_f32_16x16x32_bf16(a[i], b[j], acc[ns][i][j], 0, 0, 0);
            }
        }
        if (step < 3) {
            bf16x8 v0, v1;
#pragma unroll
            for (int e = 0; e < 4; e++) {
                v0[e] = (__bf16)fa0[e]; v0[e + 4] = (__bf16)fa1[e];
                v1[e] = (__bf16)fa2[e]; v1[e + 4] = (__bf16)fa3[e];
            }
            *(bf16x8*)(&As[p ^ 1][srow * 64 + p0]) = v0;
            *(bf16x8*)(&As[p ^ 1][srow * 64 + p1]) = v1;
        }
        __syncthreads();
    }

    int orow = gq * 4;
#pragma unroll
    for (int ns = 0; ns < 4; ns++)
#pragma unroll
        for (int i = 0; i < 2; i++)
#pragma unroll
            for (int j = 0; j < 2; j++) {
                int gn = ns * 64 + wc * 32 + j * 16 + fr;
                float bv = bias[gn];
#pragma unroll
                for (int r = 0; r < 4; r++) {
                    int gm = m0 + wr * 32 + i * 16 + orow + r;
                    C[(size_t)gm * 256 + gn] = (__bf16)(acc[ns][i][j][r] + bv);
                }
            }
}

__global__ void fillmark(float* o, int n, float v) {
    int i = blockIdx.x * blockDim.x + threadIdx.x;
    if (i < n) o[i] = v;
}

// ---------------- residual + layernorm ----------------
__global__ void ln_res(const float* a, const float* b,
                       const float* g, const float* be, float* o) {
    int row = blockIdx.x;
    int t = threadIdx.x;
    float x = a[(size_t)row * DD + t] + b[(size_t)row * DD + t];
    __shared__ float red[DD];
    red[t] = x;
    __syncthreads();
    for (int s = 128; s > 0; s >>= 1) {
        if (t < s) red[t] += red[t + s];
        __syncthreads();
    }
    float m = red[0] * (1.f / DD);
    __syncthreads();
    float d0 = x - m;
    red[t] = d0 * d0;
    __syncthreads();
    for (int s = 128; s > 0; s >>= 1) {
        if (t < s) red[t] += red[t + s];
        __syncthreads();
    }
    float v = red[0] * (1.f / DD);
    o[(size_t)row * DD + t] = d0 * rsqrtf(v + 1e-5f) * g[t] + be[t];
}

// ---------------- MFMA flash self-attention (QK packed, stride 512) ---------
#define QT 64
#define KT 64
#define NT ((NQQ + KT - 1) / KT)   // 15
#define QKLD 512

__global__ __launch_bounds__(256) void sa_attn_mfma(
    const __bf16* __restrict__ QK, const __bf16* __restrict__ V,
    float* __restrict__ O) {
    int blk = blockIdx.x;
    int tq = blk % NT;
    int bh = blk / NT;
    int h = bh % NH;
    int b = bh / NH;
    int tid = threadIdx.x;
    int lane = tid & 63;
    int wave = tid >> 6;
    int fr = lane & 15, gq = lane >> 4;
    int q0 = tq * QT;

    __shared__ __attribute__((aligned(16))) __bf16 Ks[KT][56];
    __shared__ __attribute__((aligned(16))) __bf16 Vt[HDIM][72];
    __shared__ __attribute__((aligned(16))) __bf16 Ps[4][16][72];

    int qrow = q0 + wave * 16 + fr;
    bf16x8 aq = {};
    if (qrow < NQQ)
        aq = *(const bf16x8*)(QK + ((size_t)(b * NQQ + qrow)) * QKLD + h * HDIM + gq * 8);

    f32x4 o0 = {}, o1 = {};
    float m_r[4] = {-1e30f, -1e30f, -1e30f, -1e30f};
    float l_r[4] = {0.f, 0.f, 0.f, 0.f};
    const float scale = 0.17677669529663687f;

    for (int kt = 0; kt < NT; kt++) {
        int kv0 = kt * KT;
        {
            int r = tid >> 2;
            int c8 = (tid & 3) * 8;
            int kvr = kv0 + r;
            bf16x8 kv_ = {}, vv_ = {};
            if (kvr < NQQ) {
                kv_ = *(const bf16x8*)(QK + ((size_t)(b * NQQ + kvr)) * QKLD + 256 + h * HDIM + c8);
                vv_ = *(const bf16x8*)(V + ((size_t)(b * NQQ + kvr)) * DD + h * HDIM + c8);
            }
            *(bf16x8*)(&Ks[r][c8]) = kv_;
#pragma unroll
            for (int j = 0; j < 8; j++) Vt[c8 + j][r] = vv_[j];
        }
        __syncthreads();

        f32x4 s[4];
#pragma unroll
        for (int f = 0; f < 4; f++) {
            bf16x8 bk = *(const bf16x8*)(&Ks[f * 16 + fr][gq * 8]);
            f32x4 z = {};
            s[f] = __builtin_amdgcn_mfma_f32_16x16x32_bf16(aq, bk, z, 0, 0, 0);
        }
#pragma unroll
        for (int f = 0; f < 4; f++) {
            bool valid = (kv0 + f * 16 + fr) < NQQ;
#pragma unroll
            for (int r = 0; r < 4; r++)
                s[f][r] = valid ? s[f][r] * scale : -1e30f;
        }
        float sc_[4];
#pragma unroll
        for (int r = 0; r < 4; r++) {
            float v = fmaxf(fmaxf(s[0][r], s[1][r]), fmaxf(s[2][r], s[3][r]));
            v = fmaxf(v, __shfl_xor(v, 1));
            v = fmaxf(v, __shfl_xor(v, 2));
            v = fmaxf(v, __shfl_xor(v, 4));
            v = fmaxf(v, __shfl_xor(v, 8));
            float mn = fmaxf(m_r[r], v);
            sc_[r] = expf(m_r[r] - mn);
            m_r[r] = mn;
        }
        float rs[4] = {0.f, 0.f, 0.f, 0.f};
#pragma unroll
        for (int f = 0; f < 4; f++)
#pragma unroll
            for (int r = 0; r < 4; r++) {
                float e = expf(s[f][r] - m_r[r]);
                s[f][r] = e;
                rs[r] += e;
            }
#pragma unroll
        for (int r = 0; r < 4; r++) {
            float v = rs[r];
            v += __shfl_xor(v, 1);
            v += __shfl_xor(v, 2);
            v += __shfl_xor(v, 4);
            v += __shfl_xor(v, 8);
            l_r[r] = l_r[r] * sc_[r] + v;
            o0[r] *= sc_[r];
            o1[r] *= sc_[r];
        }
#pragma unroll
        for (int f = 0; f < 4; f++)
#pragma unroll
            for (int r = 0; r < 4; r++)
                Ps[wave][gq * 4 + r][f * 16 + fr] = (__bf16)s[f][r];
#pragma unroll
        for (int c = 0; c < 2; c++) {
            bf16x8 ap = *(const bf16x8*)(&Ps[wave][fr][c * 32 + gq * 8]);
            bf16x8 bv0 = *(const bf16x8*)(&Vt[fr][c * 32 + gq * 8]);
            bf16x8 bv1 = *(const bf16x8*)(&Vt[16 + fr][c * 32 + gq * 8]);
            o0 = __builtin_amdgcn_mfma_f32_16x16x32_bf16(ap, bv0, o0, 0, 0, 0);
            o1 = __builtin_amdgcn_mfma_f32_16x16x32_bf16(ap, bv1, o1, 0, 0, 0);
        }
        __syncthreads();
    }
#pragma unroll
    for (int r = 0; r < 4; r++) {
        int qr = q0 + wave * 16 + gq * 4 + r;
        if (qr < NQQ) {
            float inv = 1.f / l_r[r];
            O[((size_t)(b * NQQ + qr)) * DD + h * HDIM + fr] = o0[r] * inv;
            O[((size_t)(b * NQQ + qr)) * DD + h * HDIM + 16 + fr] = o1[r] * inv;
        }
    }
}

// ---------------- msdeform v3: 1 query/block, 16B gathers, shfl reduce -------
#define OAW 384

__global__ __launch_bounds__(256) void msdeform3(
    const __bf16* __restrict__ val, const __bf16* __restrict__ oa,
    const float* __restrict__ ref, float* __restrict__ out) {
    int tid = threadIdx.x;
    int row = blockIdx.x;               // flat b*NQQ+q
    int b_ = row / NQQ;

    __shared__ float sx[128], sy[128], sw[128];

    if (tid < 128) {
        int h = tid >> 4;
        int lp = tid & 15;
        int l = lp >> 2;
        float logit = (float)oa[(size_t)row * OAW + 256 + h * 16 + lp];
        float ox = (float)oa[(size_t)row * OAW + h * 32 + lp * 2];
        float oy = (float)oa[(size_t)row * OAW + h * 32 + lp * 2 + 1];
        const float* rp = ref + ((size_t)row * LV + l) * 4;
        float cx = rp[0], cy = rp[1], rw = rp[2], rh = rp[3];
        float mv = logit;
        mv = fmaxf(mv, __shfl_xor(mv, 1));
        mv = fmaxf(mv, __shfl_xor(mv, 2));
        mv = fmaxf(mv, __shfl_xor(mv, 4));
        mv = fmaxf(mv, __shfl_xor(mv, 8));
        float e = expf(logit - mv);
        float sum = e;
        sum += __shfl_xor(sum, 1);
        sum += __shfl_xor(sum, 2);
        sum += __shfl_xor(sum, 4);
        sum += __shfl_xor(sum, 8);
        int Wl = 128 >> l;
        float lx = cx + ox * (1.0f / NP) * rw * 0.5f;
        float ly = cy + oy * (1.0f / NP) * rh * 0.5f;
        sx[tid] = lx * Wl - 0.5f;
        sy[tid] = ly * Wl - 0.5f;       // H == W for all levels
        sw[tid] = e / sum;
    }
    __syncthreads();

    int cpar = tid & 7;
    int dgrp = (tid >> 3) & 3;
    int h = tid >> 5;
    const int stt[4] = {0, 16384, 20480, 21504};
    const __bf16* vb = val + (size_t)b_ * SS * DD + h * HDIM + dgrp * 8;
    float facc[8] = {};
#pragma unroll
    for (int k = 0; k < 8; k++) {
        int combo = cpar * 8 + k;       // 0..63 unique per (lp,tap)
        int lp = combo >> 2;
        int tap = combo & 3;
        int l = lp >> 2;
        int Wl = 128 >> l;
        int cidx = h * 16 + lp;
        float x = sx[cidx], y = sy[cidx], w = sw[cidx];
        float x0f = floorf(x), y0f = floorf(y);
        float dx = x - x0f, dy = y - y0f;
        int xi = (int)x0f + (tap & 1);
        int yi = (int)y0f + (tap >> 1);
        float wt = ((tap & 1) ? dx : 1.f - dx) * ((tap >> 1) ? dy : 1.f - dy) * w;
        if ((xi >= 0) & (xi < Wl) & (yi >= 0) & (yi < Wl)) {
            bf16x8 t = *(const bf16x8*)(vb + (size_t)(stt[l] + yi * Wl + xi) * DD);
#pragma unroll
            for (int e = 0; e < 8; e++) facc[e] += wt * (float)t[e];
        }
    }
#pragma unroll
    for (int e = 0; e < 8; e++) {
        facc[e] += __shfl_xor(facc[e], 1);
        facc[e] += __shfl_xor(facc[e], 2);
        facc[e] += __shfl_xor(facc[e], 4);
    }
    float v = facc[0];
#pragma unroll
    for (int e = 1; e < 8; e++) if (cpar == e) v = facc[e];
    out[(size_t)row * DD + tid] = v;
}

// ---------------- launch ----------------
extern "C" void kernel_launch(void* const* d_in, const int* in_sizes, int n_in,
                              void* d_out, int out_size, void* d_ws, size_t ws_size,
                              hipStream_t stream) {
    const float* query      = (const float*)d_in[0];
    const float* query_pos  = (const float*)d_in[1];
    const float* refpts     = (const float*)d_in[2];
    const float* input_flat = (const float*)d_in[3];
    const float* sa_in_w    = (const float*)d_in[6];
    const float* sa_in_b    = (const float*)d_in[7];
    const float* sa_out_w   = (const float*)d_in[8];
    const float* sa_out_b   = (const float*)d_in[9];
    const float* norm1_g    = (const float*)d_in[10];
    const float* norm1_b    = (const float*)d_in[11];
    const float* value_w    = (const float*)d_in[12];
    const float* value_b    = (const float*)d_in[13];
    const float* off_w      = (const float*)d_in[14];
    const float* off_b      = (const float*)d_in[15];
    const float* aw_w       = (const float*)d_in[16];
    const float* aw_b       = (const float*)d_in[17];
    const float* ca_out_w   = (const float*)d_in[18];
    const float* ca_out_b   = (const float*)d_in[19];
    const float* norm2_g    = (const float*)d_in[20];
    const float* norm2_b    = (const float*)d_in[21];
    const float* lin1_w     = (const float*)d_in[22];
    const float* lin1_b     = (const float*)d_in[23];
    const float* lin2_w     = (const float*)d_in[24];
    const float* lin2_b     = (const float*)d_in[25];
    const float* norm3_g    = (const float*)d_in[26];
    const float* norm3_b    = (const float*)d_in[27];
    float* out = (float*)d_out;

    const int M = BB * NQQ;              // 3600
    const int NE = M * DD;               // 921600
    const size_t slotBytes = (size_t)NE * 4;
    const size_t wElems = 6 * 65536 + 32768 + 65536 + 2 * 524288;
    const size_t wBytes = wElems * 2;
    const size_t bigBytes = (size_t)BB * SS * DD * 2;
    const size_t needBytes = 3 * slotBytes + wBytes + bigBytes;
    if (ws_size < needBytes) {
        float mark = 1000.0f + (float)(ws_size >> 20);
        fillmark<<<(out_size + 255) / 256, 256, 0, stream>>>(out, out_size, mark);
        return;
    }

    char* wsb = (char*)d_ws;
    float* s0 = (float*)(wsb);
    float* s1 = (float*)(wsb + slotBytes);
    float* s2 = (float*)(wsb + 2 * slotBytes);
    __bf16* wb = (__bf16*)(wsb + 3 * slotBytes);
    __bf16* vbig = (__bf16*)(wsb + 3 * slotBytes + wBytes);

    __bf16* wt_q   = wb;                 // [512][256] combined with wt_k
    __bf16* wt_k   = wb + 65536;
    __bf16* wt_v   = wb + 131072;
    __bf16* wt_sa  = wb + 196608;
    __bf16* wt_val = wb + 262144;
    __bf16* wt_off = wb + 327680;        // [384][256] combined with wt_aw
    __bf16* wt_aw  = wb + 393216;
    __bf16* wt_ca  = wb + 425984;
    __bf16* wt_l1  = wb + 491520;
    __bf16* wt_l2  = wb + 1015808;

    TPtrs tp;
    tp.s[0] = sa_in_w;          tp.d[0] = wt_q;
    tp.s[1] = sa_in_w + 65536;  tp.d[1] = wt_k;
    tp.s[2] = sa_in_w + 131072; tp.d[2] = wt_v;
    tp.s[3] = sa_out_w;         tp.d[3] = wt_sa;
    tp.s[4] = value_w;          tp.d[4] = wt_val;
    tp.s[5] = off_w;            tp.d[5] = wt_off;
    tp.s[6] = aw_w;             tp.d[6] = wt_aw;
    tp.s[7] = ca_out_w;         tp.d[7] = wt_ca;
    tp.s[8] = lin1_w;           tp.d[8] = wt_l1;
    tp.s[9] = lin2_w;           tp.d[9] = wt_l2;
    transp_all<<<1504, dim3(32, 8), 0, stream>>>(tp);

    __bf16* qkbuf = (__bf16*)s1;     // [M][512]
    __bf16* Vp = (__bf16*)s2;        // [M][256]
    __bf16* oabuf = (__bf16*)s1;     // [M][384] (after attn, qk dead)

    const int mt = (M + BM - 1) / BM;    // 57
    const int mtv = (BB * SS) / BM;      // 1360
    const int BIG = 1 << 30;

    // QK projection (fused +query_pos), N=512 -> s1
    mfma_gemm<float, __bf16, 0, 1><<<dim3(8, mt), 256, 0, stream>>>(
        query, query_pos, wt_q, sa_in_b, sa_in_b, BIG, qkbuf, M, 512, DD);
    // V projection -> s2
    mfma_gemm<float, __bf16, 0, 1><<<dim3(4, mt), 256, 0, stream>>>(
        query, nullptr, wt_v, sa_in_b + 512, sa_in_b, BIG, Vp, M, DD, DD);
    // attention -> s0
    sa_attn_mfma<<<BB * NH * NT, 256, 0, stream>>>(qkbuf, Vp, s0);
    // sa projection -> s1 (f32)
    mfma_gemm<float, float, 0, 1><<<dim3(4, mt), 256, 0, stream>>>(
        s0, nullptr, wt_sa, sa_out_b, sa_out_b, BIG, s1, M, DD, DD);
    // x1 = LN(query + saproj) -> s2
    ln_res<<<M, DD, 0, stream>>>(query, s1, norm1_g, norm1_b, s2);
    // value projection -> vbig (bf16); dedicated double-buffered kernel
    value_gemm<<<mtv, 256, 0, stream>>>(input_flat, wt_val, value_b, vbig);
    // off+aw projection (fused +query_pos), N=384 -> s1
    mfma_gemm<float, __bf16, 0, 1><<<dim3(6, mt), 256, 0, stream>>>(
        s2, query_pos, wt_off, off_b, aw_b, 256, oabuf, M, OAW, DD);
    // deformable sampling -> s0
    msdeform3<<<M, 256, 0, stream>>>(vbig, oabuf, refpts, s0);
    // ca projection -> s1 (f32)
    mfma_gemm<float, float, 0, 1><<<dim3(4, mt), 256, 0, stream>>>(
        s0, nullptr, wt_ca, ca_out_b, ca_out_b, BIG, s1, M, DD, DD);
    // x2 = LN(x1 + ca) -> s1
    ln_res<<<M, DD, 0, stream>>>(s2, s1, norm2_g, norm2_b, s1);
    // ffn1 -> vbig (bf16, relu)
    mfma_gemm<float, __bf16, 1, 1><<<dim3(32, mt), 256, 0, stream>>>(
        s1, nullptr, wt_l1, lin1_b, lin1_b, BIG, vbig, M, DFF, DD);
    // ffn2 -> s0
    mfma_gemm<__bf16, float, 0, 1><<<dim3(4, mt), 256, 0, stream>>>(
        vbig, nullptr, wt_l2, lin2_b, lin2_b, BIG, s0, M, DD, DFF);
    // out = LN(x2 + ffn2)
    ln_res<<<M, DD, 0, stream>>>(s1, s0, norm3_g, norm3_b, out);
}